// Round 4
// baseline (632.906 us; speedup 1.0000x reference)
//
#include <hip/hip_runtime.h>
#include <stdint.h>

// ---------------------------------------------------------------------------
// FineReviewDecoderAttention: q/k/v proj (f32-A reg-staged bf16 MFMA GEMM,
// single-barrier counted-vmcnt pipeline + proven T2 bank-swizzle) -> fused
// attention -> out proj.  B=32 Q=128 D=1024 H=16 d=64 R=20 T=64.
// Delta vs round 16 (passed, 412.3us): A staging switched from f32
// gload_lds (16KB tiles, 1.049e7 conflicts regardless of read layout,
// 48KB LDS -> 31% occupancy) to REGISTER staging: global f32 loads ->
// v_cvt_pk_bf16_f32 (once per element) -> swizzled ds_write_b128 into the
// round-1-PROVEN bf16 tile layout (8KB/buf, measured-0-conflict reads).
// Sync: ONE barrier per K-step; ledger (order pinned by asm memory fences):
//   (a) B-gload(t+1)->nxt [2]  | fence
//   (b) A-f32 global loads(t+2)->regs [4]
//   (c) frag ds_reads + 16 MFMA on cur
//   (d) vmcnt(4): drains A(t+1) regs + B(t+1), leaves A(t+2)
//   (e) cvt A(t+1) -> ds_write nxt (writes go to buffer freed by PREV barrier)
//   (f) lgkmcnt(0); s_barrier
// Reg sets X/Y alternate with static indices (macro body, rule #20).
// Out-proj keeps the proven bf16-A gload_lds path.  attn2 unchanged.
// ---------------------------------------------------------------------------

typedef __attribute__((ext_vector_type(8))) short bf16x8;
typedef __attribute__((ext_vector_type(4))) float f32x4;
typedef __attribute__((ext_vector_type(4))) unsigned int u32x4;
typedef __attribute__((address_space(1))) const unsigned int as1_t;
typedef __attribute__((address_space(3))) unsigned int as3_t;

#define DEVI static __device__ __forceinline__

DEVI unsigned short f2bf(float f) {  // RNE f32->bf16 (finite inputs)
  unsigned int u = __float_as_uint(f);
  u += 0x7fffu + ((u >> 16) & 1u);
  return (unsigned short)(u >> 16);
}
DEVI unsigned int pack2(float a, float b) {
  return (unsigned int)f2bf(a) | ((unsigned int)f2bf(b) << 16);
}
// Round-half-up bf16 pair pack (proven rounds 7-16): a -> lo16, b -> hi16.
DEVI unsigned int pk2_rhu(float a, float b) {
  unsigned int ua = __float_as_uint(a) + 0x8000u;
  unsigned int ub = __float_as_uint(b) + 0x8000u;
  return (ua >> 16) | (ub & 0xffff0000u);
}
// HW packed f32->bf16 (RNE): a -> lo16, b -> hi16.  (round-16-proven)
DEVI unsigned int cvtpk(float a, float b) {
  unsigned int r;
  asm("v_cvt_pk_bf16_f32 %0, %1, %2" : "=v"(r) : "v"(a), "v"(b));
  return r;
}

DEVI void gload_lds16(const void* g, void* l) {
  __builtin_amdgcn_global_load_lds((as1_t*)g, (as3_t*)l, 16, 0, 0);
}

DEVI float fast_tanh(float x) {  // round-5-proven form
  float ax = fabsf(x);
  float e = __expf(2.0f * ax);
  float r = __builtin_fmaf(-2.0f, __builtin_amdgcn_rcpf(e + 1.0f), 1.0f);
  return copysignf(r, x);
}

// ------------------------- weight f32 -> bf16 ------------------------------
__global__ void cvt_w4(const float* __restrict__ w0, const float* __restrict__ w1,
                       const float* __restrict__ w2, const float* __restrict__ w3,
                       unsigned short* __restrict__ o0, unsigned short* __restrict__ o1,
                       unsigned short* __restrict__ o2, unsigned short* __restrict__ o3) {
  int i = blockIdx.x * 256 + threadIdx.x;
  if (i >= 262144) return;
  f32x4 v;
  uint2 a;
  v = ((const f32x4*)w0)[i]; a.x = pack2(v[0], v[1]); a.y = pack2(v[2], v[3]);
  *(uint2*)(o0 + 4 * (size_t)i) = a;
  v = ((const f32x4*)w1)[i]; a.x = pack2(v[0], v[1]); a.y = pack2(v[2], v[3]);
  *(uint2*)(o1 + 4 * (size_t)i) = a;
  v = ((const f32x4*)w2)[i]; a.x = pack2(v[0], v[1]); a.y = pack2(v[2], v[3]);
  *(uint2*)(o2 + 4 * (size_t)i) = a;
  v = ((const f32x4*)w3)[i]; a.x = pack2(v[0], v[1]); a.y = pack2(v[2], v[3]);
  *(uint2*)(o3 + 4 * (size_t)i) = a;
}

// ---------------- C[m,n] = sum_k A[m,k]*W[n,k] + bias[n] -------------------
// OUT_MODE: 0 = f32 row-major, 1 = bf16 row-major, 2 = bf16 per-head V^T.
// ADT: 0 = A is f32 (reg-staged: glob->cvt_pk->swizzled ds_write);
//      1 = A is bf16 (round-12-proven gload_lds path).  SC=1: x0.125.
template <int OUT_MODE, int ADT, int SC>
__global__ __launch_bounds__(256, 4) void gemm_bt(
    const void* __restrict__ Ain, const unsigned short* __restrict__ W,
    const float* __restrict__ bias, void* __restrict__ Cout, int N, int K, int nnt) {
  __shared__ __align__(16) char smem[32768];
  char* Asb = smem;          // [2][8192] bf16 A tiles (proven layout)
  char* Bsb = smem + 16384;  // [2][8192] bf16 B tiles
  const int tid = (int)threadIdx.x;
  const int lane = tid & 63, wave = tid >> 6;
  const int lm = lane & 15, l4 = lane >> 4;
  const int nb = (int)gridDim.x;
  const int bx = (int)blockIdx.x;
  const int lg = (bx & 7) * (nb >> 3) + (bx >> 3);
  const int mt = lg / nnt, nt = lg % nnt;
  const int wr = wave >> 1, wc = wave & 1;

  f32x4 zero4 = {0.f, 0.f, 0.f, 0.f};
  f32x4 acc[4][4];
#pragma unroll
  for (int i = 0; i < 4; ++i)
#pragma unroll
    for (int j = 0; j < 4; ++j) acc[i][j] = zero4;

  // ---- B staging mapping: row = tid>>2, 16B chunk = tid&3.
  // T2 swizzle: chunk (row,blk) lives at slot (row, blk ^ ((row>>1)&3)).
  // Linear LDS dest (tid*16) => pre-swizzle the GLOBAL column: scb.
  const int srow = tid >> 2, sblk = tid & 3;
  const int scb = sblk ^ ((srow >> 1) & 3);
  const unsigned short* wpg = W + (size_t)(nt * 128 + srow) * K + scb * 8;
  // fragment-read XOR key (proven): kx = (lm>>1)&3.
  const int kx = (lm >> 1) & 3;

  if (ADT == 0) {
    // ---- A reg-staging: thread owns row arow = tid>>1, f32 cols
    // [ahalf*16, ahalf*16+16) of each K-step.  After cvt: bf16 chunks
    // c = 2*ahalf, 2*ahalf+1, written at slot c ^ ((arow>>1)&3).
    const int arow = tid >> 1, ahalf = tid & 1;
    const float* apf = (const float*)Ain + (size_t)(mt * 128 + arow) * K + ahalf * 16;
    const int kxw = (arow >> 1) & 3;
    char* aw0 = Asb + arow * 64 + ((2 * ahalf) ^ kxw) * 16;
    char* aw1 = Asb + arow * 64 + ((2 * ahalf + 1) ^ kxw) * 16;
    const int NT = K >> 5;
    f32x4 X[4], Y[4];

    // ---- prologue: A(0)->X->buf0; B(0)->buf0; A(1)->Y; drain B(0) ----
#pragma unroll
    for (int u = 0; u < 4; ++u) X[u] = *(const f32x4*)(apf + u * 4);
    {
      u32x4 lo = {cvtpk(X[0][0], X[0][1]), cvtpk(X[0][2], X[0][3]),
                  cvtpk(X[1][0], X[1][1]), cvtpk(X[1][2], X[1][3])};
      u32x4 hi = {cvtpk(X[2][0], X[2][1]), cvtpk(X[2][2], X[2][3]),
                  cvtpk(X[3][0], X[3][1]), cvtpk(X[3][2], X[3][3])};
      *(u32x4*)aw0 = lo;
      *(u32x4*)aw1 = hi;
    }
    gload_lds16(wpg, Bsb + tid * 16);
    gload_lds16(wpg + (size_t)64 * K, Bsb + 4096 + tid * 16);
    asm volatile("" ::: "memory");  // pin: B(0) before A(1) loads
#pragma unroll
    for (int u = 0; u < 4; ++u) Y[u] = *(const f32x4*)(apf + 32 + u * 4);
    asm volatile("s_waitcnt vmcnt(4)" ::: "memory");   // drains B(0)
    asm volatile("s_waitcnt lgkmcnt(0)" ::: "memory"); // A(0) writes done
    asm volatile("s_barrier" ::: "memory");

    // ---- K loop: one barrier per step; SN holds A(t+1), SL gets A(t+2) ----
#define GBODY(T, SN, SL)                                                        \
    {                                                                           \
      const int t_ = (T);                                                       \
      const int cur_ = t_ & 1, nxt_ = cur_ ^ 1;                                 \
      if (t_ + 1 < NT) {                                                        \
        gload_lds16(wpg + (t_ + 1) * 32, Bsb + nxt_ * 8192 + tid * 16);         \
        gload_lds16(wpg + (size_t)64 * K + (t_ + 1) * 32,                       \
                    Bsb + nxt_ * 8192 + 4096 + tid * 16);                       \
      }                                                                         \
      asm volatile("" ::: "memory");                                            \
      if (t_ + 2 < NT) {                                                        \
        _Pragma("unroll")                                                       \
        for (int u = 0; u < 4; ++u)                                             \
          SL[u] = *(const f32x4*)(apf + (t_ + 2) * 32 + u * 4);                 \
      }                                                                         \
      bf16x8 af[4], bfr[4];                                                     \
      _Pragma("unroll")                                                         \
      for (int i = 0; i < 4; ++i)                                               \
        af[i] = *(const bf16x8*)(Asb + cur_ * 8192 +                            \
                                 (wr * 64 + i * 16 + lm) * 64 + ((l4 ^ kx) * 16)); \
      _Pragma("unroll")                                                         \
      for (int j = 0; j < 4; ++j)                                               \
        bfr[j] = *(const bf16x8*)(Bsb + cur_ * 8192 +                           \
                                  (wc * 64 + j * 16 + lm) * 64 + ((l4 ^ kx) * 16)); \
      _Pragma("unroll")                                                         \
      for (int i = 0; i < 4; ++i)                                               \
        _Pragma("unroll")                                                       \
        for (int j = 0; j < 4; ++j)                                             \
          acc[i][j] = __builtin_amdgcn_mfma_f32_16x16x32_bf16(af[i], bfr[j],    \
                                                              acc[i][j], 0, 0, 0); \
      if (t_ + 2 < NT)                                                          \
        asm volatile("s_waitcnt vmcnt(4)" ::: "memory");                        \
      else                                                                      \
        asm volatile("s_waitcnt vmcnt(0)" ::: "memory");                        \
      if (t_ + 1 < NT) {                                                        \
        u32x4 lo = {cvtpk(SN[0][0], SN[0][1]), cvtpk(SN[0][2], SN[0][3]),       \
                    cvtpk(SN[1][0], SN[1][1]), cvtpk(SN[1][2], SN[1][3])};      \
        u32x4 hi = {cvtpk(SN[2][0], SN[2][1]), cvtpk(SN[2][2], SN[2][3]),       \
                    cvtpk(SN[3][0], SN[3][1]), cvtpk(SN[3][2], SN[3][3])};      \
        *(u32x4*)(aw0 + nxt_ * 8192) = lo;                                      \
        *(u32x4*)(aw1 + nxt_ * 8192) = hi;                                      \
      }                                                                         \
      asm volatile("s_waitcnt lgkmcnt(0)" ::: "memory");                        \
      asm volatile("s_barrier" ::: "memory");                                   \
    }

    for (int t = 0; t < NT; t += 2) {
      GBODY(t, Y, X);
      GBODY(t + 1, X, Y);
    }
#undef GBODY
  } else {
    // ---- bf16-A path (round-12-proven): counted-vmcnt, swizzled tiles ----
    const unsigned short* apg =
        (const unsigned short*)Ain + (size_t)(mt * 128 + srow) * K + scb * 8;
    const int NT = K >> 5;
#pragma unroll
    for (int t0 = 0; t0 < 2; ++t0) {
      const int kt = t0 * 32;
      gload_lds16(apg + kt, Asb + t0 * 8192 + tid * 16);
      gload_lds16(apg + (size_t)64 * K + kt, Asb + t0 * 8192 + 4096 + tid * 16);
      gload_lds16(wpg + kt, Bsb + t0 * 8192 + tid * 16);
      gload_lds16(wpg + (size_t)64 * K + kt, Bsb + t0 * 8192 + 4096 + tid * 16);
    }
    int cur = 0;
    for (int t = 0; t < NT; ++t) {
      if (t + 1 < NT)
        asm volatile("s_waitcnt vmcnt(4)" ::: "memory");
      else
        asm volatile("s_waitcnt vmcnt(0)" ::: "memory");
      asm volatile("s_barrier" ::: "memory");
      bf16x8 af[4], bfr[4];
#pragma unroll
      for (int i = 0; i < 4; ++i)
        af[i] = *(const bf16x8*)(Asb + cur * 8192 + (wr * 64 + i * 16 + lm) * 64 +
                                 ((l4 ^ kx) * 16));
#pragma unroll
      for (int j = 0; j < 4; ++j)
        bfr[j] = *(const bf16x8*)(Bsb + cur * 8192 + (wc * 64 + j * 16 + lm) * 64 +
                                  ((l4 ^ kx) * 16));
#pragma unroll
      for (int i = 0; i < 4; ++i)
#pragma unroll
        for (int j = 0; j < 4; ++j)
          acc[i][j] = __builtin_amdgcn_mfma_f32_16x16x32_bf16(af[i], bfr[j], acc[i][j], 0, 0, 0);
      asm volatile("s_barrier" ::: "memory");
      if (t + 2 < NT) {
        const int kt = (t + 2) * 32;
        gload_lds16(apg + kt, Asb + cur * 8192 + tid * 16);
        gload_lds16(apg + (size_t)64 * K + kt, Asb + cur * 8192 + 4096 + tid * 16);
        gload_lds16(wpg + kt, Bsb + cur * 8192 + tid * 16);
        gload_lds16(wpg + (size_t)64 * K + kt, Bsb + cur * 8192 + 4096 + tid * 16);
      }
      cur ^= 1;
    }
  }

  const int r0 = mt * 128 + wr * 64 + l4 * 4;
  const int c0o = nt * 128 + wc * 64 + lm;
  float bb[4];
#pragma unroll
  for (int j = 0; j < 4; ++j) bb[j] = bias[c0o + j * 16];

  if (OUT_MODE < 2) {
#pragma unroll
    for (int i = 0; i < 4; ++i)
#pragma unroll
      for (int j = 0; j < 4; ++j)
#pragma unroll
        for (int p = 0; p < 4; ++p) {
          size_t idx = (size_t)(r0 + i * 16 + p) * N + (size_t)(c0o + j * 16);
          float v = acc[i][j][p] + bb[j];
          if (SC) v *= 0.125f;  // exact exponent shift; bf16(v/8) == bf16(v)/8
          if (OUT_MODE == 1)
            ((unsigned short*)Cout)[idx] = f2bf(v);
          else
            ((float*)Cout)[idx] = v;
        }
  } else {
    // V^T per-head tiles: vt[((b*20+r)*16+h)*4096 + d*64 + t], t = i*16+l4*4+p
    const int grow = mt * 128 + wr * 64;
    const int bidx = grow / 1280;
    const int rv = (grow % 1280) / 64;
    const int hh = (nt * 128 + wc * 64) / 64;
    unsigned short* vt = (unsigned short*)Cout;
    const size_t base = ((size_t)(bidx * 20 + rv) * 16 + hh) * 4096;
#pragma unroll
    for (int j = 0; j < 4; ++j) {
      const int d = lm + j * 16;
#pragma unroll
      for (int i = 0; i < 4; ++i) {
        uint2 wv;
        wv.x = pack2(acc[i][j][0] + bb[j], acc[i][j][1] + bb[j]);
        wv.y = pack2(acc[i][j][2] + bb[j], acc[i][j][3] + bb[j]);
        *(uint2*)(vt + base + (size_t)d * 64 + i * 16 + l4 * 4) = wv;
      }
    }
  }
}

// ----------------------------- fused attention -----------------------------
// One block per (h, b); 8 waves, wave w owns q rows [16w,16w+16).
// Swapped-operand MFMAs so q = lane&15 everywhere; online softmax over r.
// LDS (48KB): kv_s[2][K,V] 32KB; pa_s 16KB; q/sa^T staging overlays.
// Active-review compaction: reviews with mask==1 (when any mask==0 exists in
// row b) have pooled weight exactly 0.0f (expf(-1e30 - max) underflows) ->
// skipped entirely.  Bitmask is uniform per block (depends only on b).
__global__ __launch_bounds__(512, 4) void attn2(
    const unsigned short* __restrict__ qb, const unsigned short* __restrict__ kb,
    const unsigned short* __restrict__ vtg, const int* __restrict__ mask,
    const int* __restrict__ mask2, const float* __restrict__ sa_a,
    const float* __restrict__ sa_b, unsigned short* __restrict__ merged) {
  const int h = (int)blockIdx.x;
  const int b = (int)blockIdx.y;
  const int tid = (int)threadIdx.x;
  const int lane = tid & 63, wave = tid >> 6;
  const int lm = lane & 15, l4 = lane >> 4;
  const int sw = (lm & 7) << 4;

  __shared__ unsigned short kv_s[2][2][64 * 64];  // [buf][0=K [t][d], 1=V^T [d][t]]
  __shared__ unsigned short pa_s[8 * 16 * 64];    // wave-private P/att rows

  char* kvb0 = (char*)kv_s;          // buf stride 16384; V^T at +8192
  char* qreg = (char*)kv_s + 16384;  // q staging region = buf1 (dead after hoist)
  char* satb = (char*)pa_s;          // sa^T staging (dead after hoist)

  // ---- active-review bitmask (uniform across the block) ----
  unsigned am = 0u;
#pragma unroll
  for (int rr = 0; rr < 20; ++rr)
    am |= (mask[b * 20 + rr] == 0) ? (1u << rr) : 0u;
  // az (= some review has mask==0) => only those reviews survive; else all.
  const unsigned act = am ? am : 0xFFFFFu;

  // ---- stage Q into qreg (pre-swizzled source columns) ----
#pragma unroll
  for (int s = 0; s < 2; ++s) {
    int idx = s * 512 + tid, row = idx >> 3, blk = idx & 7;
    int cb = blk ^ (row & 7);
    gload_lds16(qb + (size_t)(b * 128 + row) * 1024 + h * 64 + cb * 8, qreg + idx * 16);
  }
  // ---- stage sa^T into satb: sat[jj][d] = sa_a[d][jj], swizzled ----
#pragma unroll
  for (int s = 0; s < 8; ++s) {
    int idx = s * 512 + tid, jj = idx & 63, d = idx >> 6;
    *(unsigned short*)(satb + jj * 128 + ((d * 2) ^ ((jj & 7) << 4))) =
        f2bf(sa_a[d * 64 + jj]);
  }
  // ---- stage first ACTIVE review K/V into buf0 ----
  const int srow = tid >> 3, sblk = tid & 7;
  const int scb = sblk ^ (srow & 7);
  int r = (int)__builtin_ctz(act);
  unsigned rem = act & (act - 1u);
  gload_lds16(kb + ((size_t)(b * 20 + r) * 64 + srow) * 1024 + h * 64 + scb * 8,
              kvb0 + tid * 16);
  gload_lds16(vtg + ((size_t)(b * 20 + r) * 16 + h) * 4096 + srow * 64 + scb * 8,
              kvb0 + 8192 + tid * 16);

  f32x4 sbv[4];
#pragma unroll
  for (int i = 0; i < 4; ++i) sbv[i] = *(const f32x4*)(sa_b + i * 16 + l4 * 4);

  __syncthreads();  // qreg, satb, buf0 all visible

  // ---- hoist Q B-fragments and sa^T A-fragments to registers ----
  const char* qrp = qreg + (wave * 16 + lm) * 128;
  bf16x8 qf[2];
  qf[0] = *(const bf16x8*)(qrp + ((l4 * 16) ^ sw));
  qf[1] = *(const bf16x8*)(qrp + ((64 + l4 * 16) ^ sw));
  bf16x8 sfr[2][4];
#pragma unroll
  for (int kk = 0; kk < 2; ++kk)
#pragma unroll
    for (int i = 0; i < 4; ++i)
      sfr[kk][i] = *(const bf16x8*)(satb + (i * 16 + lm) * 128 +
                                    ((kk * 64 + l4 * 16) ^ sw));
  asm volatile("s_waitcnt lgkmcnt(0)" ::: "memory");  // hoist reads retired
  __syncthreads();  // all waves done -> qreg/satb reusable as buf1 / P-rows

  char* pw = (char*)pa_s + wave * 2048 + lm * 128;  // wave-private row q=lm

  f32x4 zero4 = {0.f, 0.f, 0.f, 0.f};
  f32x4 Pacc[4];
#pragma unroll
  for (int i = 0; i < 4; ++i) Pacc[i] = zero4;
  float m_run = -3.0e38f, s_run = 0.0f;

  int it = 0;
  for (;;) {
    const int pb = it & 1;
    if (it) __syncthreads();  // buf[pb] staged; all waves done with buf[1-pb]
    const int nr = rem ? (int)__builtin_ctz(rem) : -1;
    if (nr >= 0) {  // stage next active review (flies under this one's compute)
      const int nbuf = pb ^ 1;
      gload_lds16(kb + ((size_t)(b * 20 + nr) * 64 + srow) * 1024 + h * 64 + scb * 8,
                  kvb0 + nbuf * 16384 + tid * 16);
      gload_lds16(vtg + ((size_t)(b * 20 + nr) * 16 + h) * 4096 + srow * 64 + scb * 8,
                  kvb0 + nbuf * 16384 + 8192 + tid * 16);
    }
    const char* kbse = kvb0 + pb * 16384;
    const char* vbse = kvb0 + pb * 16384 + 8192;

    // ---- S^T = mfma(K, Q): rows t, col q (q pre-scaled by 1/8) ----
    f32x4 sc[4];
#pragma unroll
    for (int i = 0; i < 4; ++i) sc[i] = zero4;
    __builtin_amdgcn_s_setprio(1);
#pragma unroll
    for (int kk = 0; kk < 2; ++kk) {
      bf16x8 kf[4];
#pragma unroll
      for (int i = 0; i < 4; ++i)
        kf[i] = *(const bf16x8*)(kbse + (i * 16 + lm) * 128 + ((kk * 64 + l4 * 16) ^ sw));
#pragma unroll
      for (int i = 0; i < 4; ++i)
        sc[i] = __builtin_amdgcn_mfma_f32_16x16x32_bf16(kf[i], qf[kk], sc[i], 0, 0, 0);
    }
    __builtin_amdgcn_s_setprio(0);

    // ---- token mask (scores already scaled) + softmax over t ----
    const int mbase = (b * 20 + r) * 64;
#pragma unroll
    for (int i = 0; i < 4; ++i) {
      int4 m2 = *(const int4*)(mask2 + mbase + i * 16 + l4 * 4);
      sc[i][0] = (m2.x == 0) ? -1e20f : sc[i][0];
      sc[i][1] = (m2.y == 0) ? -1e20f : sc[i][1];
      sc[i][2] = (m2.z == 0) ? -1e20f : sc[i][2];
      sc[i][3] = (m2.w == 0) ? -1e20f : sc[i][3];
    }
    float mx = sc[0][0];
#pragma unroll
    for (int i = 0; i < 4; ++i)
#pragma unroll
      for (int p = 0; p < 4; ++p) mx = fmaxf(mx, sc[i][p]);
    mx = fmaxf(mx, __shfl_xor(mx, 16));
    mx = fmaxf(mx, __shfl_xor(mx, 32));
    float sum = 0.f;
#pragma unroll
    for (int i = 0; i < 4; ++i)
#pragma unroll
      for (int p = 0; p < 4; ++p) {
        float e = __expf(sc[i][p] - mx);
        sc[i][p] = e;
        sum += e;
      }
    sum += __shfl_xor(sum, 16);
    sum += __shfl_xor(sum, 32);
    const float pinv = __builtin_amdgcn_rcpf(sum);

    // ---- P -> wave-private LDS [q][t], packed 8B swizzled writes ----
#pragma unroll
    for (int i = 0; i < 4; ++i) {
      uint2 wv;
      wv.x = pk2_rhu(sc[i][0] * pinv, sc[i][1] * pinv);
      wv.y = pk2_rhu(sc[i][2] * pinv, sc[i][3] * pinv);
      *(uint2*)(pw + ((i * 32 + l4 * 8) ^ sw)) = wv;
    }

    // ---- att^T = mfma(V^T, P): rows d, col q ----
    f32x4 av[4];
#pragma unroll
    for (int i = 0; i < 4; ++i) av[i] = zero4;
    __builtin_amdgcn_s_setprio(1);
#pragma unroll
    for (int kk = 0; kk < 2; ++kk) {
      bf16x8 pf = *(const bf16x8*)(pw + ((kk * 64 + l4 * 16) ^ sw));
      bf16x8 vf[4];
#pragma unroll
      for (int i = 0; i < 4; ++i)
        vf[i] = *(const bf16x8*)(vbse + (i * 16 + lm) * 128 + ((kk * 64 + l4 * 16) ^ sw));
#pragma unroll
      for (int i = 0; i < 4; ++i)
        av[i] = __builtin_amdgcn_mfma_f32_16x16x32_bf16(vf[i], pf, av[i], 0, 0, 0);
    }
    __builtin_amdgcn_s_setprio(0);

    // ---- att -> same wave-private LDS [q][d] (P already consumed) ----
#pragma unroll
    for (int i = 0; i < 4; ++i) {
      uint2 wv;
      wv.x = pk2_rhu(av[i][0], av[i][1]);
      wv.y = pk2_rhu(av[i][2], av[i][3]);
      *(uint2*)(pw + ((i * 32 + l4 * 8) ^ sw)) = wv;
    }

    // ---- e^T = mfma(sa^T, att): rows jj, col q ----
    f32x4 ep[4];
#pragma unroll
    for (int i = 0; i < 4; ++i) ep[i] = zero4;
    __builtin_amdgcn_s_setprio(1);
#pragma unroll
    for (int kk = 0; kk < 2; ++kk) {
      bf16x8 afr = *(const bf16x8*)(pw + ((kk * 64 + l4 * 16) ^ sw));
#pragma unroll
      for (int i = 0; i < 4; ++i)
        ep[i] = __builtin_amdgcn_mfma_f32_16x16x32_bf16(sfr[kk][i], afr, ep[i], 0, 0, 0);
    }
    __builtin_amdgcn_s_setprio(0);
    float a = 0.f;
#pragma unroll
    for (int i = 0; i < 4; ++i)
#pragma unroll
      for (int p = 0; p < 4; ++p) a += fast_tanh(ep[i][p]) * sbv[i][p];
    a += __shfl_xor(a, 16);
    a += __shfl_xor(a, 32);

    // ---- exact online softmax update over active reviews ----
    // All surviving reviews have add_mask == 0, so e_r = a directly.
    const float e_r = a;
    const float mnew = fmaxf(m_run, e_r);
    const float scl = __expf(m_run - mnew);
    const float w = __expf(e_r - mnew);
    s_run = s_run * scl + w;
#pragma unroll
    for (int i = 0; i < 4; ++i)
#pragma unroll
      for (int p = 0; p < 4; ++p) Pacc[i][p] = Pacc[i][p] * scl + w * av[i][p];
    m_run = mnew;

    if (nr < 0) break;
    r = nr;
    rem &= rem - 1u;
    ++it;
  }

  // ---- merged[b*128+q][h*64+d] = bf16(Pacc / s) ----
  const float inv_s = __builtin_amdgcn_rcpf(s_run);
  unsigned short* mrow = merged + (size_t)(b * 128 + wave * 16 + lm) * 1024 + h * 64;
#pragma unroll
  for (int i = 0; i < 4; ++i) {
    uint2 o;
    o.x = pk2_rhu(Pacc[i][0] * inv_s, Pacc[i][1] * inv_s);
    o.y = pk2_rhu(Pacc[i][2] * inv_s, Pacc[i][3] * inv_s);
    *(uint2*)(mrow + i * 16 + l4 * 4) = o;
  }
}

// ---------------------------------------------------------------------------
extern "C" void kernel_launch(void* const* d_in, const int* in_sizes, int n_in,
                              void* d_out, int out_size, void* d_ws, size_t ws_size,
                              hipStream_t stream) {
  (void)in_sizes; (void)n_in; (void)out_size; (void)ws_size;
  const float* query = (const float*)d_in[0];
  const float* key   = (const float*)d_in[1];
  const float* value = (const float*)d_in[2];
  const int*   mask  = (const int*)d_in[3];
  const int*   mask2 = (const int*)d_in[4];
  const float* Wq = (const float*)d_in[5];
  const float* bq = (const float*)d_in[6];
  const float* Wk = (const float*)d_in[7];
  const float* bk = (const float*)d_in[8];
  const float* Wv = (const float*)d_in[9];
  const float* bv = (const float*)d_in[10];
  const float* Wo = (const float*)d_in[11];
  const float* bo = (const float*)d_in[12];
  const float* sa_a = (const float*)d_in[13];
  const float* sa_b = (const float*)d_in[14];

  char* ws = (char*)d_ws;
  size_t off = 0;
  auto carve = [&](size_t bytes) -> char* {
    char* p = ws + off;
    off += (bytes + 255) & ~(size_t)255;
    return p;
  };
  unsigned short* wq_b = (unsigned short*)carve((size_t)1024 * 1024 * 2);
  unsigned short* wk_b = (unsigned short*)carve((size_t)1024 * 1024 * 2);
  unsigned short* wv_b = (unsigned short*)carve((size_t)1024 * 1024 * 2);
  unsigned short* wo_b = (unsigned short*)carve((size_t)1024 * 1024 * 2);
  unsigned short* q_b  = (unsigned short*)carve((size_t)4096 * 1024 * 2);
  unsigned short* k_b  = (unsigned short*)carve((size_t)40960 * 1024 * 2);
  unsigned short* vt_g = (unsigned short*)carve((size_t)40960 * 1024 * 2);
  unsigned short* mrg  = (unsigned short*)carve((size_t)4096 * 1024 * 2);

  cvt_w4<<<1024, 256, 0, stream>>>(Wq, Wk, Wv, Wo, wq_b, wk_b, wv_b, wo_b);

  // f32-A reg-staged GEMMs (no cvt_bf16 passes)
  gemm_bt<1, 0, 1><<<dim3(32 * 8), 256, 0, stream>>>(query, wq_b, bq, q_b, 1024, 1024, 8);
  gemm_bt<1, 0, 0><<<dim3(320 * 8), 256, 0, stream>>>(key, wk_b, bk, k_b, 1024, 1024, 8);
  gemm_bt<2, 0, 0><<<dim3(320 * 8), 256, 0, stream>>>(value, wv_b, bv, vt_g, 1024, 1024, 8);

  attn2<<<dim3(16, 32), 512, 0, stream>>>(q_b, k_b, vt_g, mask, mask2, sa_a, sa_b, mrg);

  // out projection: A (mrg) is bf16 -> proven bf16-A path
  gemm_bt<0, 1, 0><<<dim3(32 * 8), 256, 0, stream>>>(mrg, wo_b, bo, d_out, 1024, 1024, 8);
}

// Round 5
// 395.239 us; speedup vs baseline: 1.6013x; 1.6013x over previous
//
#include <hip/hip_runtime.h>
#include <stdint.h>

// ---------------------------------------------------------------------------
// FineReviewDecoderAttention: compact active reviews -> q/k/v proj (f32-A
// direct-staged bf16 MFMA GEMM, counted-vmcnt 2-buffer pipeline + T2 swizzle
// + sub-stagger) -> fused attention -> out proj.
// B=32 Q=128 D=1024 H=16 d=64 R=20 T=64.
// Delta vs round 17 (reg-staging REVERTED: launch_bounds(256,4) caps VGPR at
// 128 -> 482MB scratch spill).  Base = round 16 (best, 412.3us) plus:
//  (1) ACTIVE-REVIEW COMPACTION for K/V GEMMs: attn2 provably never reads
//      K/V of inactive reviews (round-14 bit-exact skip).  compact_rv (1
//      wave, ballot/popcount) builds the ascending active-slot list (odd
//      count padded with duplicate last slot -> duplicate tile writes
//      bit-identical bytes, benign).  K/V gemm tiles map local rows through
//      cs0/cs1 = cmp[1+2mt..]; blocks with 2mt>=cnt exit before any barrier
//      (uniform).  E[active]=52% -> ~48% of K/V GEMM work skipped.
//  (2) A-tile SUB-STAGGER: round-2/3 conflicts (1.049e7, identical across
//      different read layouts) come from sub0/sub1 stacked at 8KB (bank-
//      aligned): 4 lanes sharing a row collide 4-way.  Stagger sub1 +64B
//      (16 banks) -> even/odd-row bank halves disjoint -> <=2 lanes/slot.
//      ABUF 16384->16448, LDS 49280B (occupancy unchanged, 3 blocks/CU).
// attn2 / out-proj / cvt_w4 unchanged.
// ---------------------------------------------------------------------------

typedef __attribute__((ext_vector_type(8))) short bf16x8;
typedef __attribute__((ext_vector_type(4))) float f32x4;
typedef __attribute__((ext_vector_type(4))) unsigned int u32x4;
typedef __attribute__((address_space(1))) const unsigned int as1_t;
typedef __attribute__((address_space(3))) unsigned int as3_t;

#define DEVI static __device__ __forceinline__

DEVI unsigned short f2bf(float f) {  // RNE f32->bf16 (finite inputs)
  unsigned int u = __float_as_uint(f);
  u += 0x7fffu + ((u >> 16) & 1u);
  return (unsigned short)(u >> 16);
}
DEVI unsigned int pack2(float a, float b) {
  return (unsigned int)f2bf(a) | ((unsigned int)f2bf(b) << 16);
}
// Round-half-up bf16 pair pack (proven rounds 7-16): a -> lo16, b -> hi16.
DEVI unsigned int pk2_rhu(float a, float b) {
  unsigned int ua = __float_as_uint(a) + 0x8000u;
  unsigned int ub = __float_as_uint(b) + 0x8000u;
  return (ua >> 16) | (ub & 0xffff0000u);
}
// HW packed f32->bf16 (RNE): a -> lo16, b -> hi16.  (round-16-proven)
DEVI unsigned int cvtpk(float a, float b) {
  unsigned int r;
  asm("v_cvt_pk_bf16_f32 %0, %1, %2" : "=v"(r) : "v"(a), "v"(b));
  return r;
}

DEVI bf16x8 u2bf(u32x4 v) {
  union { u32x4 u; bf16x8 b; } c;
  c.u = v;
  return c.b;
}

DEVI void gload_lds16(const void* g, void* l) {
  __builtin_amdgcn_global_load_lds((as1_t*)g, (as3_t*)l, 16, 0, 0);
}

DEVI float fast_tanh(float x) {  // round-5-proven form
  float ax = fabsf(x);
  float e = __expf(2.0f * ax);
  float r = __builtin_fmaf(-2.0f, __builtin_amdgcn_rcpf(e + 1.0f), 1.0f);
  return copysignf(r, x);
}

// ------------------------- weight f32 -> bf16 ------------------------------
__global__ void cvt_w4(const float* __restrict__ w0, const float* __restrict__ w1,
                       const float* __restrict__ w2, const float* __restrict__ w3,
                       unsigned short* __restrict__ o0, unsigned short* __restrict__ o1,
                       unsigned short* __restrict__ o2, unsigned short* __restrict__ o3) {
  int i = blockIdx.x * 256 + threadIdx.x;
  if (i >= 262144) return;
  f32x4 v;
  uint2 a;
  v = ((const f32x4*)w0)[i]; a.x = pack2(v[0], v[1]); a.y = pack2(v[2], v[3]);
  *(uint2*)(o0 + 4 * (size_t)i) = a;
  v = ((const f32x4*)w1)[i]; a.x = pack2(v[0], v[1]); a.y = pack2(v[2], v[3]);
  *(uint2*)(o1 + 4 * (size_t)i) = a;
  v = ((const f32x4*)w2)[i]; a.x = pack2(v[0], v[1]); a.y = pack2(v[2], v[3]);
  *(uint2*)(o2 + 4 * (size_t)i) = a;
  v = ((const f32x4*)w3)[i]; a.x = pack2(v[0], v[1]); a.y = pack2(v[2], v[3]);
  *(uint2*)(o3 + 4 * (size_t)i) = a;
}

// ------------------- active-review slot compaction -------------------------
// out[0] = count; out[1..count] = ascending active slots s = b*20+r;
// out[1+count] = last active slot (pad; used only when count is odd).
// active(s): if batch b has any mask==0 -> (mask[s]==0), else all active.
// Mirrors attn2's bit-exact skip criterion (round-14).
__global__ void compact_rv(const int* __restrict__ mask, int* __restrict__ out) {
  const int lane = (int)threadIdx.x;  // 64 threads, 1 block
  __shared__ int azs[32];
  if (lane < 32) {
    int z = 0;
#pragma unroll
    for (int r = 0; r < 20; ++r) z |= (mask[lane * 20 + r] == 0) ? 1 : 0;
    azs[lane] = z;
  }
  __syncthreads();
  int base = 0;
  int lasts = 0;
  for (int it = 0; it < 10; ++it) {
    const int s = it * 64 + lane;
    const int bb = s / 20;
    const int actv = azs[bb] ? ((mask[s] == 0) ? 1 : 0) : 1;
    unsigned long long bal = __ballot(actv);
    const int off = (int)__popcll(bal & ((1ull << lane) - 1ull));
    if (actv) {
      out[1 + base + off] = s;
      lasts = s;
    }
    base += (int)__popcll(bal);
  }
#pragma unroll
  for (int d = 1; d < 64; d <<= 1) {
    int o = __shfl_xor(lasts, d);
    lasts = lasts > o ? lasts : o;
  }
  if (lane == 0) {
    out[0] = base;
    out[1 + base] = lasts;  // pad for odd count
  }
}

// ---------------- C[m,n] = sum_k A[m,k]*W[n,k] + bias[n] -------------------
// OUT_MODE: 0 = f32 row-major, 1 = bf16 row-major, 2 = bf16 per-head V^T.
// ADT: 0 = A is f32 (direct gload_lds staging, cvt_pk at frag load);
//      1 = A is bf16 (round-12-proven gload_lds path).  SC=1: x0.125.
// CMP=1: M-tiles indirect through compacted active-slot list (64-row slots);
//        blocks beyond the active count exit early.
template <int OUT_MODE, int ADT, int SC, int CMP>
__global__ __launch_bounds__(256, 4) void gemm_bt(
    const void* __restrict__ Ain, const unsigned short* __restrict__ W,
    const float* __restrict__ bias, void* __restrict__ Cout, int N, int K, int nnt,
    const int* __restrict__ cmp) {
  // ADT=1: A bf16 2x8KB + B 2x8KB = 32KB.
  // ADT=0: A f32 2x16448 (sub1 staggered +64B) + B 2x8KB = 49280B.
  __shared__ __align__(16) char smem[ADT ? 32768 : 49280];
  char* Asb = smem;
  char* Bsb = smem + (ADT ? 16384 : 32896);
  const int ABUF = 16448;  // per-buffer A bytes (ADT=0)
  const int tid = (int)threadIdx.x;
  const int lane = tid & 63, wave = tid >> 6;
  const int lm = lane & 15, l4 = lane >> 4;
  const int nb = (int)gridDim.x;
  const int bx = (int)blockIdx.x;
  const int lg = (bx & 7) * (nb >> 3) + (bx >> 3);
  const int mt = lg / nnt, nt = lg % nnt;
  const int wr = wave >> 1, wc = wave & 1;

  // ---- M-row slot mapping (64-row slots; tile = slots cs0, cs1) ----
  int cs0 = 2 * mt, cs1 = 2 * mt + 1;
  if (CMP) {
    const int cnt = cmp[0];
    if (2 * mt >= cnt) return;  // uniform exit before any barrier
    cs0 = cmp[1 + 2 * mt];
    cs1 = cmp[2 + 2 * mt];
  }

  f32x4 zero4 = {0.f, 0.f, 0.f, 0.f};
  f32x4 acc[4][4];
#pragma unroll
  for (int i = 0; i < 4; ++i)
#pragma unroll
    for (int j = 0; j < 4; ++j) acc[i][j] = zero4;

  // ---- B staging mapping: row = tid>>2, 16B chunk = tid&3.
  // T2 swizzle: chunk (row,blk) lives at slot (row, blk ^ ((row>>1)&3)).
  // Linear LDS dest (tid*16) => pre-swizzle the GLOBAL column: scb.
  const int srow = tid >> 2, sblk = tid & 3;
  const int scb = sblk ^ ((srow >> 1) & 3);
  const unsigned short* wpg = W + (size_t)(nt * 128 + srow) * K + scb * 8;
  // fragment-read XOR key (proven): kx = (lm>>1)&3.
  const int kx = (lm >> 1) & 3;

  if (ADT == 0) {
    // ---- A f32 staging: layout [sub][row][slot], 64B rows, sub1 at +8256
    // (+64B stagger).  Thread stages row tid>>2 of both slots: chunk u=0/1 ->
    // sub0 (K-half 0) rows of cs0/cs1; u=2/3 -> sub1 (K-half 1).
    // Pre-swizzled global column: chunk (tid&3) ^ ((tid>>3)&3).
    const float* apf0 = (const float*)Ain +
                        ((size_t)cs0 * 64 + (tid >> 2)) * K +
                        ((tid & 3) ^ ((tid >> 3) & 3)) * 4;
    const float* apf1 = (const float*)Ain +
                        ((size_t)cs1 * 64 + (tid >> 2)) * K +
                        ((tid & 3) ^ ((tid >> 3) & 3)) * 4;
    const int NT = K >> 5;
#pragma unroll
    for (int t0 = 0; t0 < 2; ++t0) {
      const int kt = t0 * 32;
      gload_lds16(apf0 + kt, Asb + t0 * ABUF + tid * 16);
      gload_lds16(apf1 + kt, Asb + t0 * ABUF + 4096 + tid * 16);
      gload_lds16(apf0 + 16 + kt, Asb + t0 * ABUF + 8256 + tid * 16);
      gload_lds16(apf1 + 16 + kt, Asb + t0 * ABUF + 12352 + tid * 16);
      gload_lds16(wpg + kt, Bsb + t0 * 8192 + tid * 16);
      gload_lds16(wpg + (size_t)64 * K + kt, Bsb + t0 * 8192 + 4096 + tid * 16);
    }
    int cur = 0;
    const int asub = (l4 >> 1) * 8256;  // K-half this lane reads (staggered)
    const int c0r = (l4 & 1) * 2;       // first of 2 global chunks
    const int rd0 = ((c0r ^ kx) * 16);  // swizzled slots
    const int rd1 = (((c0r + 1) ^ kx) * 16);
    for (int t = 0; t < NT; ++t) {
      if (t + 1 < NT)
        asm volatile("s_waitcnt vmcnt(6)" ::: "memory");
      else
        asm volatile("s_waitcnt vmcnt(0)" ::: "memory");
      asm volatile("s_barrier" ::: "memory");
      bf16x8 af[4], bfr[4];
#pragma unroll
      for (int i = 0; i < 4; ++i) {
        const char* ab = Asb + cur * ABUF + asub + (wr * 64 + i * 16 + lm) * 64;
        f32x4 lo = *(const f32x4*)(ab + rd0);
        f32x4 hi = *(const f32x4*)(ab + rd1);
        u32x4 pv = {cvtpk(lo[0], lo[1]), cvtpk(lo[2], lo[3]),
                    cvtpk(hi[0], hi[1]), cvtpk(hi[2], hi[3])};
        af[i] = u2bf(pv);
      }
#pragma unroll
      for (int j = 0; j < 4; ++j)
        bfr[j] = *(const bf16x8*)(Bsb + cur * 8192 + (wc * 64 + j * 16 + lm) * 64 +
                                  ((l4 ^ kx) * 16));
#pragma unroll
      for (int i = 0; i < 4; ++i)
#pragma unroll
        for (int j = 0; j < 4; ++j)
          acc[i][j] = __builtin_amdgcn_mfma_f32_16x16x32_bf16(af[i], bfr[j], acc[i][j], 0, 0, 0);
      asm volatile("s_barrier" ::: "memory");
      if (t + 2 < NT) {
        const int kt = (t + 2) * 32;
        gload_lds16(apf0 + kt, Asb + cur * ABUF + tid * 16);
        gload_lds16(apf1 + kt, Asb + cur * ABUF + 4096 + tid * 16);
        gload_lds16(apf0 + 16 + kt, Asb + cur * ABUF + 8256 + tid * 16);
        gload_lds16(apf1 + 16 + kt, Asb + cur * ABUF + 12352 + tid * 16);
        gload_lds16(wpg + kt, Bsb + cur * 8192 + tid * 16);
        gload_lds16(wpg + (size_t)64 * K + kt, Bsb + cur * 8192 + 4096 + tid * 16);
      }
      cur ^= 1;
    }
  } else {
    // ---- bf16-A path (round-12-proven): counted-vmcnt, swizzled tiles ----
    const unsigned short* apg =
        (const unsigned short*)Ain + (size_t)(mt * 128 + srow) * K + scb * 8;
    const int NT = K >> 5;
#pragma unroll
    for (int t0 = 0; t0 < 2; ++t0) {
      const int kt = t0 * 32;
      gload_lds16(apg + kt, Asb + t0 * 8192 + tid * 16);
      gload_lds16(apg + (size_t)64 * K + kt, Asb + t0 * 8192 + 4096 + tid * 16);
      gload_lds16(wpg + kt, Bsb + t0 * 8192 + tid * 16);
      gload_lds16(wpg + (size_t)64 * K + kt, Bsb + t0 * 8192 + 4096 + tid * 16);
    }
    int cur = 0;
    for (int t = 0; t < NT; ++t) {
      if (t + 1 < NT)
        asm volatile("s_waitcnt vmcnt(4)" ::: "memory");
      else
        asm volatile("s_waitcnt vmcnt(0)" ::: "memory");
      asm volatile("s_barrier" ::: "memory");
      bf16x8 af[4], bfr[4];
#pragma unroll
      for (int i = 0; i < 4; ++i)
        af[i] = *(const bf16x8*)(Asb + cur * 8192 + (wr * 64 + i * 16 + lm) * 64 +
                                 ((l4 ^ kx) * 16));
#pragma unroll
      for (int j = 0; j < 4; ++j)
        bfr[j] = *(const bf16x8*)(Bsb + cur * 8192 + (wc * 64 + j * 16 + lm) * 64 +
                                  ((l4 ^ kx) * 16));
#pragma unroll
      for (int i = 0; i < 4; ++i)
#pragma unroll
        for (int j = 0; j < 4; ++j)
          acc[i][j] = __builtin_amdgcn_mfma_f32_16x16x32_bf16(af[i], bfr[j], acc[i][j], 0, 0, 0);
      asm volatile("s_barrier" ::: "memory");
      if (t + 2 < NT) {
        const int kt = (t + 2) * 32;
        gload_lds16(apg + kt, Asb + cur * 8192 + tid * 16);
        gload_lds16(apg + (size_t)64 * K + kt, Asb + cur * 8192 + 4096 + tid * 16);
        gload_lds16(wpg + kt, Bsb + cur * 8192 + tid * 16);
        gload_lds16(wpg + (size_t)64 * K + kt, Bsb + cur * 8192 + 4096 + tid * 16);
      }
      cur ^= 1;
    }
  }

  const int c0o = nt * 128 + wc * 64 + lm;
  float bb[4];
#pragma unroll
  for (int j = 0; j < 4; ++j) bb[j] = bias[c0o + j * 16];
  const int mslot = wr ? cs1 : cs0;  // this wave's 64-row slot

  if (OUT_MODE < 2) {
#pragma unroll
    for (int i = 0; i < 4; ++i)
#pragma unroll
      for (int j = 0; j < 4; ++j)
#pragma unroll
        for (int p = 0; p < 4; ++p) {
          size_t grow = (size_t)mslot * 64 + (l4 * 4 + i * 16 + p);
          size_t idx = grow * N + (size_t)(c0o + j * 16);
          float v = acc[i][j][p] + bb[j];
          if (SC) v *= 0.125f;  // exact exponent shift; bf16(v/8) == bf16(v)/8
          if (OUT_MODE == 1)
            ((unsigned short*)Cout)[idx] = f2bf(v);
          else
            ((float*)Cout)[idx] = v;
        }
  } else {
    // V^T per-head tiles: vt[(slot*16+h)*4096 + d*64 + t], t = i*16+l4*4+p
    const int hh = (nt * 128 + wc * 64) / 64;
    unsigned short* vt = (unsigned short*)Cout;
    const size_t base = ((size_t)mslot * 16 + hh) * 4096;
#pragma unroll
    for (int j = 0; j < 4; ++j) {
      const int d = lm + j * 16;
#pragma unroll
      for (int i = 0; i < 4; ++i) {
        uint2 wv;
        wv.x = pack2(acc[i][j][0] + bb[j], acc[i][j][1] + bb[j]);
        wv.y = pack2(acc[i][j][2] + bb[j], acc[i][j][3] + bb[j]);
        *(uint2*)(vt + base + (size_t)d * 64 + i * 16 + l4 * 4) = wv;
      }
    }
  }
}

// ----------------------------- fused attention -----------------------------
// One block per (h, b); 8 waves, wave w owns q rows [16w,16w+16).
// Swapped-operand MFMAs so q = lane&15 everywhere; online softmax over r.
// LDS (48KB): kv_s[2][K,V] 32KB; pa_s 16KB; q/sa^T staging overlays.
// Active-review compaction: reviews with mask==1 (when any mask==0 exists in
// row b) have pooled weight exactly 0.0f (expf(-1e30 - max) underflows) ->
// skipped entirely.  Bitmask is uniform per block (depends only on b).
__global__ __launch_bounds__(512, 4) void attn2(
    const unsigned short* __restrict__ qb, const unsigned short* __restrict__ kb,
    const unsigned short* __restrict__ vtg, const int* __restrict__ mask,
    const int* __restrict__ mask2, const float* __restrict__ sa_a,
    const float* __restrict__ sa_b, unsigned short* __restrict__ merged) {
  const int h = (int)blockIdx.x;
  const int b = (int)blockIdx.y;
  const int tid = (int)threadIdx.x;
  const int lane = tid & 63, wave = tid >> 6;
  const int lm = lane & 15, l4 = lane >> 4;
  const int sw = (lm & 7) << 4;

  __shared__ unsigned short kv_s[2][2][64 * 64];  // [buf][0=K [t][d], 1=V^T [d][t]]
  __shared__ unsigned short pa_s[8 * 16 * 64];    // wave-private P/att rows

  char* kvb0 = (char*)kv_s;          // buf stride 16384; V^T at +8192
  char* qreg = (char*)kv_s + 16384;  // q staging region = buf1 (dead after hoist)
  char* satb = (char*)pa_s;          // sa^T staging (dead after hoist)

  // ---- active-review bitmask (uniform across the block) ----
  unsigned am = 0u;
#pragma unroll
  for (int rr = 0; rr < 20; ++rr)
    am |= (mask[b * 20 + rr] == 0) ? (1u << rr) : 0u;
  // az (= some review has mask==0) => only those reviews survive; else all.
  const unsigned act = am ? am : 0xFFFFFu;

  // ---- stage Q into qreg (pre-swizzled source columns) ----
#pragma unroll
  for (int s = 0; s < 2; ++s) {
    int idx = s * 512 + tid, row = idx >> 3, blk = idx & 7;
    int cb = blk ^ (row & 7);
    gload_lds16(qb + (size_t)(b * 128 + row) * 1024 + h * 64 + cb * 8, qreg + idx * 16);
  }
  // ---- stage sa^T into satb: sat[jj][d] = sa_a[d][jj], swizzled ----
#pragma unroll
  for (int s = 0; s < 8; ++s) {
    int idx = s * 512 + tid, jj = idx & 63, d = idx >> 6;
    *(unsigned short*)(satb + jj * 128 + ((d * 2) ^ ((jj & 7) << 4))) =
        f2bf(sa_a[d * 64 + jj]);
  }
  // ---- stage first ACTIVE review K/V into buf0 ----
  const int srow = tid >> 3, sblk = tid & 7;
  const int scb = sblk ^ (srow & 7);
  int r = (int)__builtin_ctz(act);
  unsigned rem = act & (act - 1u);
  gload_lds16(kb + ((size_t)(b * 20 + r) * 64 + srow) * 1024 + h * 64 + scb * 8,
              kvb0 + tid * 16);
  gload_lds16(vtg + ((size_t)(b * 20 + r) * 16 + h) * 4096 + srow * 64 + scb * 8,
              kvb0 + 8192 + tid * 16);

  f32x4 sbv[4];
#pragma unroll
  for (int i = 0; i < 4; ++i) sbv[i] = *(const f32x4*)(sa_b + i * 16 + l4 * 4);

  __syncthreads();  // qreg, satb, buf0 all visible

  // ---- hoist Q B-fragments and sa^T A-fragments to registers ----
  const char* qrp = qreg + (wave * 16 + lm) * 128;
  bf16x8 qf[2];
  qf[0] = *(const bf16x8*)(qrp + ((l4 * 16) ^ sw));
  qf[1] = *(const bf16x8*)(qrp + ((64 + l4 * 16) ^ sw));
  bf16x8 sfr[2][4];
#pragma unroll
  for (int kk = 0; kk < 2; ++kk)
#pragma unroll
    for (int i = 0; i < 4; ++i)
      sfr[kk][i] = *(const bf16x8*)(satb + (i * 16 + lm) * 128 +
                                    ((kk * 64 + l4 * 16) ^ sw));
  asm volatile("s_waitcnt lgkmcnt(0)" ::: "memory");  // hoist reads retired
  __syncthreads();  // all waves done -> qreg/satb reusable as buf1 / P-rows

  char* pw = (char*)pa_s + wave * 2048 + lm * 128;  // wave-private row q=lm

  f32x4 zero4 = {0.f, 0.f, 0.f, 0.f};
  f32x4 Pacc[4];
#pragma unroll
  for (int i = 0; i < 4; ++i) Pacc[i] = zero4;
  float m_run = -3.0e38f, s_run = 0.0f;

  int it = 0;
  for (;;) {
    const int pb = it & 1;
    if (it) __syncthreads();  // buf[pb] staged; all waves done with buf[1-pb]
    const int nr = rem ? (int)__builtin_ctz(rem) : -1;
    if (nr >= 0) {  // stage next active review (flies under this one's compute)
      const int nbuf = pb ^ 1;
      gload_lds16(kb + ((size_t)(b * 20 + nr) * 64 + srow) * 1024 + h * 64 + scb * 8,
                  kvb0 + nbuf * 16384 + tid * 16);
      gload_lds16(vtg + ((size_t)(b * 20 + nr) * 16 + h) * 4096 + srow * 64 + scb * 8,
                  kvb0 + nbuf * 16384 + 8192 + tid * 16);
    }
    const char* kbse = kvb0 + pb * 16384;
    const char* vbse = kvb0 + pb * 16384 + 8192;

    // ---- S^T = mfma(K, Q): rows t, col q (q pre-scaled by 1/8) ----
    f32x4 sc[4];
#pragma unroll
    for (int i = 0; i < 4; ++i) sc[i] = zero4;
    __builtin_amdgcn_s_setprio(1);
#pragma unroll
    for (int kk = 0; kk < 2; ++kk) {
      bf16x8 kf[4];
#pragma unroll
      for (int i = 0; i < 4; ++i)
        kf[i] = *(const bf16x8*)(kbse + (i * 16 + lm) * 128 + ((kk * 64 + l4 * 16) ^ sw));
#pragma unroll
      for (int i = 0; i < 4; ++i)
        sc[i] = __builtin_amdgcn_mfma_f32_16x16x32_bf16(kf[i], qf[kk], sc[i], 0, 0, 0);
    }
    __builtin_amdgcn_s_setprio(0);

    // ---- token mask (scores already scaled) + softmax over t ----
    const int mbase = (b * 20 + r) * 64;
#pragma unroll
    for (int i = 0; i < 4; ++i) {
      int4 m2 = *(const int4*)(mask2 + mbase + i * 16 + l4 * 4);
      sc[i][0] = (m2.x == 0) ? -1e20f : sc[i][0];
      sc[i][1] = (m2.y == 0) ? -1e20f : sc[i][1];
      sc[i][2] = (m2.z == 0) ? -1e20f : sc[i][2];
      sc[i][3] = (m2.w == 0) ? -1e20f : sc[i][3];
    }
    float mx = sc[0][0];
#pragma unroll
    for (int i = 0; i < 4; ++i)
#pragma unroll
      for (int p = 0; p < 4; ++p) mx = fmaxf(mx, sc[i][p]);
    mx = fmaxf(mx, __shfl_xor(mx, 16));
    mx = fmaxf(mx, __shfl_xor(mx, 32));
    float sum = 0.f;
#pragma unroll
    for (int i = 0; i < 4; ++i)
#pragma unroll
      for (int p = 0; p < 4; ++p) {
        float e = __expf(sc[i][p] - mx);
        sc[i][p] = e;
        sum += e;
      }
    sum += __shfl_xor(sum, 16);
    sum += __shfl_xor(sum, 32);
    const float pinv = __builtin_amdgcn_rcpf(sum);

    // ---- P -> wave-private LDS [q][t], packed 8B swizzled writes ----
#pragma unroll
    for (int i = 0; i < 4; ++i) {
      uint2 wv;
      wv.x = pk2_rhu(sc[i][0] * pinv, sc[i][1] * pinv);
      wv.y = pk2_rhu(sc[i][2] * pinv, sc[i][3] * pinv);
      *(uint2*)(pw + ((i * 32 + l4 * 8) ^ sw)) = wv;
    }

    // ---- att^T = mfma(V^T, P): rows d, col q ----
    f32x4 av[4];
#pragma unroll
    for (int i = 0; i < 4; ++i) av[i] = zero4;
    __builtin_amdgcn_s_setprio(1);
#pragma unroll
    for (int kk = 0; kk < 2; ++kk) {
      bf16x8 pf = *(const bf16x8*)(pw + ((kk * 64 + l4 * 16) ^ sw));
      bf16x8 vf[4];
#pragma unroll
      for (int i = 0; i < 4; ++i)
        vf[i] = *(const bf16x8*)(vbse + (i * 16 + lm) * 128 + ((kk * 64 + l4 * 16) ^ sw));
#pragma unroll
      for (int i = 0; i < 4; ++i)
        av[i] = __builtin_amdgcn_mfma_f32_16x16x32_bf16(vf[i], pf, av[i], 0, 0, 0);
    }
    __builtin_amdgcn_s_setprio(0);

    // ---- att -> same wave-private LDS [q][d] (P already consumed) ----
#pragma unroll
    for (int i = 0; i < 4; ++i) {
      uint2 wv;
      wv.x = pk2_rhu(av[i][0], av[i][1]);
      wv.y = pk2_rhu(av[i][2], av[i][3]);
      *(uint2*)(pw + ((i * 32 + l4 * 8) ^ sw)) = wv;
    }

    // ---- e^T = mfma(sa^T, att): rows jj, col q ----
    f32x4 ep[4];
#pragma unroll
    for (int i = 0; i < 4; ++i) ep[i] = zero4;
    __builtin_amdgcn_s_setprio(1);
#pragma unroll
    for (int kk = 0; kk < 2; ++kk) {
      bf16x8 afr = *(const bf16x8*)(pw + ((kk * 64 + l4 * 16) ^ sw));
#pragma unroll
      for (int i = 0; i < 4; ++i)
        ep[i] = __builtin_amdgcn_mfma_f32_16x16x32_bf16(sfr[kk][i], afr, ep[i], 0, 0, 0);
    }
    __builtin_amdgcn_s_setprio(0);
    float a = 0.f;
#pragma unroll
    for (int i = 0; i < 4; ++i)
#pragma unroll
      for (int p = 0; p < 4; ++p) a += fast_tanh(ep[i][p]) * sbv[i][p];
    a += __shfl_xor(a, 16);
    a += __shfl_xor(a, 32);

    // ---- exact online softmax update over active reviews ----
    // All surviving reviews have add_mask == 0, so e_r = a directly.
    const float e_r = a;
    const float mnew = fmaxf(m_run, e_r);
    const float scl = __expf(m_run - mnew);
    const float w = __expf(e_r - mnew);
    s_run = s_run * scl + w;
#pragma unroll
    for (int i = 0; i < 4; ++i)
#pragma unroll
      for (int p = 0; p < 4; ++p) Pacc[i][p] = Pacc[i][p] * scl + w * av[i][p];
    m_run = mnew;

    if (nr < 0) break;
    r = nr;
    rem &= rem - 1u;
    ++it;
  }

  // ---- merged[b*128+q][h*64+d] = bf16(Pacc / s) ----
  const float inv_s = __builtin_amdgcn_rcpf(s_run);
  unsigned short* mrow = merged + (size_t)(b * 128 + wave * 16 + lm) * 1024 + h * 64;
#pragma unroll
  for (int i = 0; i < 4; ++i) {
    uint2 o;
    o.x = pk2_rhu(Pacc[i][0] * inv_s, Pacc[i][1] * inv_s);
    o.y = pk2_rhu(Pacc[i][2] * inv_s, Pacc[i][3] * inv_s);
    *(uint2*)(mrow + i * 16 + l4 * 4) = o;
  }
}

// ---------------------------------------------------------------------------
extern "C" void kernel_launch(void* const* d_in, const int* in_sizes, int n_in,
                              void* d_out, int out_size, void* d_ws, size_t ws_size,
                              hipStream_t stream) {
  (void)in_sizes; (void)n_in; (void)out_size; (void)ws_size;
  const float* query = (const float*)d_in[0];
  const float* key   = (const float*)d_in[1];
  const float* value = (const float*)d_in[2];
  const int*   mask  = (const int*)d_in[3];
  const int*   mask2 = (const int*)d_in[4];
  const float* Wq = (const float*)d_in[5];
  const float* bq = (const float*)d_in[6];
  const float* Wk = (const float*)d_in[7];
  const float* bk = (const float*)d_in[8];
  const float* Wv = (const float*)d_in[9];
  const float* bv = (const float*)d_in[10];
  const float* Wo = (const float*)d_in[11];
  const float* bo = (const float*)d_in[12];
  const float* sa_a = (const float*)d_in[13];
  const float* sa_b = (const float*)d_in[14];

  char* ws = (char*)d_ws;
  size_t off = 0;
  auto carve = [&](size_t bytes) -> char* {
    char* p = ws + off;
    off += (bytes + 255) & ~(size_t)255;
    return p;
  };
  unsigned short* wq_b = (unsigned short*)carve((size_t)1024 * 1024 * 2);
  unsigned short* wk_b = (unsigned short*)carve((size_t)1024 * 1024 * 2);
  unsigned short* wv_b = (unsigned short*)carve((size_t)1024 * 1024 * 2);
  unsigned short* wo_b = (unsigned short*)carve((size_t)1024 * 1024 * 2);
  unsigned short* q_b  = (unsigned short*)carve((size_t)4096 * 1024 * 2);
  unsigned short* k_b  = (unsigned short*)carve((size_t)40960 * 1024 * 2);
  unsigned short* vt_g = (unsigned short*)carve((size_t)40960 * 1024 * 2);
  unsigned short* mrg  = (unsigned short*)carve((size_t)4096 * 1024 * 2);
  int* cmp = (int*)carve(4096);

  cvt_w4<<<1024, 256, 0, stream>>>(Wq, Wk, Wv, Wo, wq_b, wk_b, wv_b, wo_b);
  compact_rv<<<1, 64, 0, stream>>>(mask, cmp);

  // f32-A direct GEMMs (no cvt_bf16 passes); K/V compacted to active reviews
  gemm_bt<1, 0, 1, 0><<<dim3(32 * 8), 256, 0, stream>>>(query, wq_b, bq, q_b, 1024, 1024, 8, cmp);
  gemm_bt<1, 0, 0, 1><<<dim3(320 * 8), 256, 0, stream>>>(key, wk_b, bk, k_b, 1024, 1024, 8, cmp);
  gemm_bt<2, 0, 0, 1><<<dim3(320 * 8), 256, 0, stream>>>(value, wv_b, bv, vt_g, 1024, 1024, 8, cmp);

  attn2<<<dim3(16, 32), 512, 0, stream>>>(q_b, k_b, vt_g, mask, mask2, sa_a, sa_b, mrg);

  // out projection: A (mrg) is bf16 -> proven bf16-A path
  gemm_bt<0, 1, 0, 0><<<dim3(32 * 8), 256, 0, stream>>>(mrg, wo_b, bo, d_out, 1024, 1024, 8, cmp);
}

// Round 6
// 325.128 us; speedup vs baseline: 1.9466x; 1.2156x over previous
//
#include <hip/hip_runtime.h>
#include <stdint.h>

// ---------------------------------------------------------------------------
// FineReviewDecoderAttention: compact active reviews -> q/k/v proj (f32-A
// direct-staged bf16 MFMA GEMM, counted-vmcnt 2-buffer pipeline + T2 swizzle)
// -> fused attention -> out proj.  B=32 Q=128 D=1024 H=16 d=64 R=20 T=64.
// Delta vs round 18 (passed, 395.2us): CMP=1 kernels use the PLAIN tile
// mapping mt=bx/nnt, nt=bx%nnt.  Round-18's XCD swizzle mapped every active
// compacted tile (2mt < cnt ~ 320 -> lg < 1280 -> bx&7 < 4) onto XCDs 0-3:
// XCDs 4-7 idle, occupancy 31%->13%, half the work ran in ~the same time.
// Plain mapping: active blocks are bx < ~1280, bx&7 cycles all 8 XCDs ->
// compacted work spreads across the whole chip.  CMP=0 (Q/out-proj) keeps
// the proven swizzle.  Everything else identical to round 18.
// ---------------------------------------------------------------------------

typedef __attribute__((ext_vector_type(8))) short bf16x8;
typedef __attribute__((ext_vector_type(4))) float f32x4;
typedef __attribute__((ext_vector_type(4))) unsigned int u32x4;
typedef __attribute__((address_space(1))) const unsigned int as1_t;
typedef __attribute__((address_space(3))) unsigned int as3_t;

#define DEVI static __device__ __forceinline__

DEVI unsigned short f2bf(float f) {  // RNE f32->bf16 (finite inputs)
  unsigned int u = __float_as_uint(f);
  u += 0x7fffu + ((u >> 16) & 1u);
  return (unsigned short)(u >> 16);
}
DEVI unsigned int pack2(float a, float b) {
  return (unsigned int)f2bf(a) | ((unsigned int)f2bf(b) << 16);
}
// Round-half-up bf16 pair pack (proven rounds 7-18): a -> lo16, b -> hi16.
DEVI unsigned int pk2_rhu(float a, float b) {
  unsigned int ua = __float_as_uint(a) + 0x8000u;
  unsigned int ub = __float_as_uint(b) + 0x8000u;
  return (ua >> 16) | (ub & 0xffff0000u);
}
// HW packed f32->bf16 (RNE): a -> lo16, b -> hi16.  (round-16-proven)
DEVI unsigned int cvtpk(float a, float b) {
  unsigned int r;
  asm("v_cvt_pk_bf16_f32 %0, %1, %2" : "=v"(r) : "v"(a), "v"(b));
  return r;
}

DEVI bf16x8 u2bf(u32x4 v) {
  union { u32x4 u; bf16x8 b; } c;
  c.u = v;
  return c.b;
}

DEVI void gload_lds16(const void* g, void* l) {
  __builtin_amdgcn_global_load_lds((as1_t*)g, (as3_t*)l, 16, 0, 0);
}

DEVI float fast_tanh(float x) {  // round-5-proven form
  float ax = fabsf(x);
  float e = __expf(2.0f * ax);
  float r = __builtin_fmaf(-2.0f, __builtin_amdgcn_rcpf(e + 1.0f), 1.0f);
  return copysignf(r, x);
}

// ------------------------- weight f32 -> bf16 ------------------------------
__global__ void cvt_w4(const float* __restrict__ w0, const float* __restrict__ w1,
                       const float* __restrict__ w2, const float* __restrict__ w3,
                       unsigned short* __restrict__ o0, unsigned short* __restrict__ o1,
                       unsigned short* __restrict__ o2, unsigned short* __restrict__ o3) {
  int i = blockIdx.x * 256 + threadIdx.x;
  if (i >= 262144) return;
  f32x4 v;
  uint2 a;
  v = ((const f32x4*)w0)[i]; a.x = pack2(v[0], v[1]); a.y = pack2(v[2], v[3]);
  *(uint2*)(o0 + 4 * (size_t)i) = a;
  v = ((const f32x4*)w1)[i]; a.x = pack2(v[0], v[1]); a.y = pack2(v[2], v[3]);
  *(uint2*)(o1 + 4 * (size_t)i) = a;
  v = ((const f32x4*)w2)[i]; a.x = pack2(v[0], v[1]); a.y = pack2(v[2], v[3]);
  *(uint2*)(o2 + 4 * (size_t)i) = a;
  v = ((const f32x4*)w3)[i]; a.x = pack2(v[0], v[1]); a.y = pack2(v[2], v[3]);
  *(uint2*)(o3 + 4 * (size_t)i) = a;
}

// ------------------- active-review slot compaction -------------------------
// out[0] = count; out[1..count] = ascending active slots s = b*20+r;
// out[1+count] = last active slot (pad; used only when count is odd).
// active(s): if batch b has any mask==0 -> (mask[s]==0), else all active.
// Mirrors attn2's bit-exact skip criterion (round-14).
__global__ void compact_rv(const int* __restrict__ mask, int* __restrict__ out) {
  const int lane = (int)threadIdx.x;  // 64 threads, 1 block
  __shared__ int azs[32];
  if (lane < 32) {
    int z = 0;
#pragma unroll
    for (int r = 0; r < 20; ++r) z |= (mask[lane * 20 + r] == 0) ? 1 : 0;
    azs[lane] = z;
  }
  __syncthreads();
  int base = 0;
  int lasts = 0;
  for (int it = 0; it < 10; ++it) {
    const int s = it * 64 + lane;
    const int bb = s / 20;
    const int actv = azs[bb] ? ((mask[s] == 0) ? 1 : 0) : 1;
    unsigned long long bal = __ballot(actv);
    const int off = (int)__popcll(bal & ((1ull << lane) - 1ull));
    if (actv) {
      out[1 + base + off] = s;
      lasts = s;
    }
    base += (int)__popcll(bal);
  }
#pragma unroll
  for (int d = 1; d < 64; d <<= 1) {
    int o = __shfl_xor(lasts, d);
    lasts = lasts > o ? lasts : o;
  }
  if (lane == 0) {
    out[0] = base;
    out[1 + base] = lasts;  // pad for odd count
  }
}

// ---------------- C[m,n] = sum_k A[m,k]*W[n,k] + bias[n] -------------------
// OUT_MODE: 0 = f32 row-major, 1 = bf16 row-major, 2 = bf16 per-head V^T.
// ADT: 0 = A is f32 (direct gload_lds staging, cvt_pk at frag load);
//      1 = A is bf16 (round-12-proven gload_lds path).  SC=1: x0.125.
// CMP=1: M-tiles indirect through compacted active-slot list (64-row slots);
//        blocks beyond the active count exit early; PLAIN tile mapping (no
//        XCD swizzle -- active prefix must round-robin across XCDs).
template <int OUT_MODE, int ADT, int SC, int CMP>
__global__ __launch_bounds__(256, 4) void gemm_bt(
    const void* __restrict__ Ain, const unsigned short* __restrict__ W,
    const float* __restrict__ bias, void* __restrict__ Cout, int N, int K, int nnt,
    const int* __restrict__ cmp) {
  // ADT=1: A bf16 2x8KB + B 2x8KB = 32KB.
  // ADT=0: A f32 2x16448 (sub1 staggered +64B) + B 2x8KB = 49280B.
  __shared__ __align__(16) char smem[ADT ? 32768 : 49280];
  char* Asb = smem;
  char* Bsb = smem + (ADT ? 16384 : 32896);
  const int ABUF = 16448;  // per-buffer A bytes (ADT=0)
  const int tid = (int)threadIdx.x;
  const int lane = tid & 63, wave = tid >> 6;
  const int lm = lane & 15, l4 = lane >> 4;
  const int nb = (int)gridDim.x;
  const int bx = (int)blockIdx.x;
  // CMP=1: plain mapping (active prefix bx < 8*tiles spreads over all XCDs).
  // CMP=0: proven XCD-swizzled mapping.
  const int lg = CMP ? bx : ((bx & 7) * (nb >> 3) + (bx >> 3));
  const int mt = lg / nnt, nt = lg % nnt;
  const int wr = wave >> 1, wc = wave & 1;

  // ---- M-row slot mapping (64-row slots; tile = slots cs0, cs1) ----
  int cs0 = 2 * mt, cs1 = 2 * mt + 1;
  if (CMP) {
    const int cnt = cmp[0];
    if (2 * mt >= cnt) return;  // uniform exit before any barrier
    cs0 = cmp[1 + 2 * mt];
    cs1 = cmp[2 + 2 * mt];
  }

  f32x4 zero4 = {0.f, 0.f, 0.f, 0.f};
  f32x4 acc[4][4];
#pragma unroll
  for (int i = 0; i < 4; ++i)
#pragma unroll
    for (int j = 0; j < 4; ++j) acc[i][j] = zero4;

  // ---- B staging mapping: row = tid>>2, 16B chunk = tid&3.
  // T2 swizzle: chunk (row,blk) lives at slot (row, blk ^ ((row>>1)&3)).
  // Linear LDS dest (tid*16) => pre-swizzle the GLOBAL column: scb.
  const int srow = tid >> 2, sblk = tid & 3;
  const int scb = sblk ^ ((srow >> 1) & 3);
  const unsigned short* wpg = W + (size_t)(nt * 128 + srow) * K + scb * 8;
  // fragment-read XOR key (proven): kx = (lm>>1)&3.
  const int kx = (lm >> 1) & 3;

  if (ADT == 0) {
    // ---- A f32 staging: layout [sub][row][slot], 64B rows, sub1 at +8256
    // (+64B stagger).  Thread stages row tid>>2 of both slots: chunk u=0/1 ->
    // sub0 (K-half 0) rows of cs0/cs1; u=2/3 -> sub1 (K-half 1).
    // Pre-swizzled global column: chunk (tid&3) ^ ((tid>>3)&3).
    const float* apf0 = (const float*)Ain +
                        ((size_t)cs0 * 64 + (tid >> 2)) * K +
                        ((tid & 3) ^ ((tid >> 3) & 3)) * 4;
    const float* apf1 = (const float*)Ain +
                        ((size_t)cs1 * 64 + (tid >> 2)) * K +
                        ((tid & 3) ^ ((tid >> 3) & 3)) * 4;
    const int NT = K >> 5;
#pragma unroll
    for (int t0 = 0; t0 < 2; ++t0) {
      const int kt = t0 * 32;
      gload_lds16(apf0 + kt, Asb + t0 * ABUF + tid * 16);
      gload_lds16(apf1 + kt, Asb + t0 * ABUF + 4096 + tid * 16);
      gload_lds16(apf0 + 16 + kt, Asb + t0 * ABUF + 8256 + tid * 16);
      gload_lds16(apf1 + 16 + kt, Asb + t0 * ABUF + 12352 + tid * 16);
      gload_lds16(wpg + kt, Bsb + t0 * 8192 + tid * 16);
      gload_lds16(wpg + (size_t)64 * K + kt, Bsb + t0 * 8192 + 4096 + tid * 16);
    }
    int cur = 0;
    const int asub = (l4 >> 1) * 8256;  // K-half this lane reads (staggered)
    const int c0r = (l4 & 1) * 2;       // first of 2 global chunks
    const int rd0 = ((c0r ^ kx) * 16);  // swizzled slots
    const int rd1 = (((c0r + 1) ^ kx) * 16);
    for (int t = 0; t < NT; ++t) {
      if (t + 1 < NT)
        asm volatile("s_waitcnt vmcnt(6)" ::: "memory");
      else
        asm volatile("s_waitcnt vmcnt(0)" ::: "memory");
      asm volatile("s_barrier" ::: "memory");
      bf16x8 af[4], bfr[4];
#pragma unroll
      for (int i = 0; i < 4; ++i) {
        const char* ab = Asb + cur * ABUF + asub + (wr * 64 + i * 16 + lm) * 64;
        f32x4 lo = *(const f32x4*)(ab + rd0);
        f32x4 hi = *(const f32x4*)(ab + rd1);
        u32x4 pv = {cvtpk(lo[0], lo[1]), cvtpk(lo[2], lo[3]),
                    cvtpk(hi[0], hi[1]), cvtpk(hi[2], hi[3])};
        af[i] = u2bf(pv);
      }
#pragma unroll
      for (int j = 0; j < 4; ++j)
        bfr[j] = *(const bf16x8*)(Bsb + cur * 8192 + (wc * 64 + j * 16 + lm) * 64 +
                                  ((l4 ^ kx) * 16));
#pragma unroll
      for (int i = 0; i < 4; ++i)
#pragma unroll
        for (int j = 0; j < 4; ++j)
          acc[i][j] = __builtin_amdgcn_mfma_f32_16x16x32_bf16(af[i], bfr[j], acc[i][j], 0, 0, 0);
      asm volatile("s_barrier" ::: "memory");
      if (t + 2 < NT) {
        const int kt = (t + 2) * 32;
        gload_lds16(apf0 + kt, Asb + cur * ABUF + tid * 16);
        gload_lds16(apf1 + kt, Asb + cur * ABUF + 4096 + tid * 16);
        gload_lds16(apf0 + 16 + kt, Asb + cur * ABUF + 8256 + tid * 16);
        gload_lds16(apf1 + 16 + kt, Asb + cur * ABUF + 12352 + tid * 16);
        gload_lds16(wpg + kt, Bsb + cur * 8192 + tid * 16);
        gload_lds16(wpg + (size_t)64 * K + kt, Bsb + cur * 8192 + 4096 + tid * 16);
      }
      cur ^= 1;
    }
  } else {
    // ---- bf16-A path (round-12-proven): counted-vmcnt, swizzled tiles ----
    const unsigned short* apg =
        (const unsigned short*)Ain + (size_t)(mt * 128 + srow) * K + scb * 8;
    const int NT = K >> 5;
#pragma unroll
    for (int t0 = 0; t0 < 2; ++t0) {
      const int kt = t0 * 32;
      gload_lds16(apg + kt, Asb + t0 * 8192 + tid * 16);
      gload_lds16(apg + (size_t)64 * K + kt, Asb + t0 * 8192 + 4096 + tid * 16);
      gload_lds16(wpg + kt, Bsb + t0 * 8192 + tid * 16);
      gload_lds16(wpg + (size_t)64 * K + kt, Bsb + t0 * 8192 + 4096 + tid * 16);
    }
    int cur = 0;
    for (int t = 0; t < NT; ++t) {
      if (t + 1 < NT)
        asm volatile("s_waitcnt vmcnt(4)" ::: "memory");
      else
        asm volatile("s_waitcnt vmcnt(0)" ::: "memory");
      asm volatile("s_barrier" ::: "memory");
      bf16x8 af[4], bfr[4];
#pragma unroll
      for (int i = 0; i < 4; ++i)
        af[i] = *(const bf16x8*)(Asb + cur * 8192 + (wr * 64 + i * 16 + lm) * 64 +
                                 ((l4 ^ kx) * 16));
#pragma unroll
      for (int j = 0; j < 4; ++j)
        bfr[j] = *(const bf16x8*)(Bsb + cur * 8192 + (wc * 64 + j * 16 + lm) * 64 +
                                  ((l4 ^ kx) * 16));
#pragma unroll
      for (int i = 0; i < 4; ++i)
#pragma unroll
        for (int j = 0; j < 4; ++j)
          acc[i][j] = __builtin_amdgcn_mfma_f32_16x16x32_bf16(af[i], bfr[j], acc[i][j], 0, 0, 0);
      asm volatile("s_barrier" ::: "memory");
      if (t + 2 < NT) {
        const int kt = (t + 2) * 32;
        gload_lds16(apg + kt, Asb + cur * 8192 + tid * 16);
        gload_lds16(apg + (size_t)64 * K + kt, Asb + cur * 8192 + 4096 + tid * 16);
        gload_lds16(wpg + kt, Bsb + cur * 8192 + tid * 16);
        gload_lds16(wpg + (size_t)64 * K + kt, Bsb + cur * 8192 + 4096 + tid * 16);
      }
      cur ^= 1;
    }
  }

  const int c0o = nt * 128 + wc * 64 + lm;
  float bb[4];
#pragma unroll
  for (int j = 0; j < 4; ++j) bb[j] = bias[c0o + j * 16];
  const int mslot = wr ? cs1 : cs0;  // this wave's 64-row slot

  if (OUT_MODE < 2) {
#pragma unroll
    for (int i = 0; i < 4; ++i)
#pragma unroll
      for (int j = 0; j < 4; ++j)
#pragma unroll
        for (int p = 0; p < 4; ++p) {
          size_t grow = (size_t)mslot * 64 + (l4 * 4 + i * 16 + p);
          size_t idx = grow * N + (size_t)(c0o + j * 16);
          float v = acc[i][j][p] + bb[j];
          if (SC) v *= 0.125f;  // exact exponent shift; bf16(v/8) == bf16(v)/8
          if (OUT_MODE == 1)
            ((unsigned short*)Cout)[idx] = f2bf(v);
          else
            ((float*)Cout)[idx] = v;
        }
  } else {
    // V^T per-head tiles: vt[(slot*16+h)*4096 + d*64 + t], t = i*16+l4*4+p
    const int hh = (nt * 128 + wc * 64) / 64;
    unsigned short* vt = (unsigned short*)Cout;
    const size_t base = ((size_t)mslot * 16 + hh) * 4096;
#pragma unroll
    for (int j = 0; j < 4; ++j) {
      const int d = lm + j * 16;
#pragma unroll
      for (int i = 0; i < 4; ++i) {
        uint2 wv;
        wv.x = pack2(acc[i][j][0] + bb[j], acc[i][j][1] + bb[j]);
        wv.y = pack2(acc[i][j][2] + bb[j], acc[i][j][3] + bb[j]);
        *(uint2*)(vt + base + (size_t)d * 64 + i * 16 + l4 * 4) = wv;
      }
    }
  }
}

// ----------------------------- fused attention -----------------------------
// One block per (h, b); 8 waves, wave w owns q rows [16w,16w+16).
// Swapped-operand MFMAs so q = lane&15 everywhere; online softmax over r.
// LDS (48KB): kv_s[2][K,V] 32KB; pa_s 16KB; q/sa^T staging overlays.
// Active-review compaction: reviews with mask==1 (when any mask==0 exists in
// row b) have pooled weight exactly 0.0f (expf(-1e30 - max) underflows) ->
// skipped entirely.  Bitmask is uniform per block (depends only on b).
__global__ __launch_bounds__(512, 4) void attn2(
    const unsigned short* __restrict__ qb, const unsigned short* __restrict__ kb,
    const unsigned short* __restrict__ vtg, const int* __restrict__ mask,
    const int* __restrict__ mask2, const float* __restrict__ sa_a,
    const float* __restrict__ sa_b, unsigned short* __restrict__ merged) {
  const int h = (int)blockIdx.x;
  const int b = (int)blockIdx.y;
  const int tid = (int)threadIdx.x;
  const int lane = tid & 63, wave = tid >> 6;
  const int lm = lane & 15, l4 = lane >> 4;
  const int sw = (lm & 7) << 4;

  __shared__ unsigned short kv_s[2][2][64 * 64];  // [buf][0=K [t][d], 1=V^T [d][t]]
  __shared__ unsigned short pa_s[8 * 16 * 64];    // wave-private P/att rows

  char* kvb0 = (char*)kv_s;          // buf stride 16384; V^T at +8192
  char* qreg = (char*)kv_s + 16384;  // q staging region = buf1 (dead after hoist)
  char* satb = (char*)pa_s;          // sa^T staging (dead after hoist)

  // ---- active-review bitmask (uniform across the block) ----
  unsigned am = 0u;
#pragma unroll
  for (int rr = 0; rr < 20; ++rr)
    am |= (mask[b * 20 + rr] == 0) ? (1u << rr) : 0u;
  // az (= some review has mask==0) => only those reviews survive; else all.
  const unsigned act = am ? am : 0xFFFFFu;

  // ---- stage Q into qreg (pre-swizzled source columns) ----
#pragma unroll
  for (int s = 0; s < 2; ++s) {
    int idx = s * 512 + tid, row = idx >> 3, blk = idx & 7;
    int cb = blk ^ (row & 7);
    gload_lds16(qb + (size_t)(b * 128 + row) * 1024 + h * 64 + cb * 8, qreg + idx * 16);
  }
  // ---- stage sa^T into satb: sat[jj][d] = sa_a[d][jj], swizzled ----
#pragma unroll
  for (int s = 0; s < 8; ++s) {
    int idx = s * 512 + tid, jj = idx & 63, d = idx >> 6;
    *(unsigned short*)(satb + jj * 128 + ((d * 2) ^ ((jj & 7) << 4))) =
        f2bf(sa_a[d * 64 + jj]);
  }
  // ---- stage first ACTIVE review K/V into buf0 ----
  const int srow = tid >> 3, sblk = tid & 7;
  const int scb = sblk ^ (srow & 7);
  int r = (int)__builtin_ctz(act);
  unsigned rem = act & (act - 1u);
  gload_lds16(kb + ((size_t)(b * 20 + r) * 64 + srow) * 1024 + h * 64 + scb * 8,
              kvb0 + tid * 16);
  gload_lds16(vtg + ((size_t)(b * 20 + r) * 16 + h) * 4096 + srow * 64 + scb * 8,
              kvb0 + 8192 + tid * 16);

  f32x4 sbv[4];
#pragma unroll
  for (int i = 0; i < 4; ++i) sbv[i] = *(const f32x4*)(sa_b + i * 16 + l4 * 4);

  __syncthreads();  // qreg, satb, buf0 all visible

  // ---- hoist Q B-fragments and sa^T A-fragments to registers ----
  const char* qrp = qreg + (wave * 16 + lm) * 128;
  bf16x8 qf[2];
  qf[0] = *(const bf16x8*)(qrp + ((l4 * 16) ^ sw));
  qf[1] = *(const bf16x8*)(qrp + ((64 + l4 * 16) ^ sw));
  bf16x8 sfr[2][4];
#pragma unroll
  for (int kk = 0; kk < 2; ++kk)
#pragma unroll
    for (int i = 0; i < 4; ++i)
      sfr[kk][i] = *(const bf16x8*)(satb + (i * 16 + lm) * 128 +
                                    ((kk * 64 + l4 * 16) ^ sw));
  asm volatile("s_waitcnt lgkmcnt(0)" ::: "memory");  // hoist reads retired
  __syncthreads();  // all waves done -> qreg/satb reusable as buf1 / P-rows

  char* pw = (char*)pa_s + wave * 2048 + lm * 128;  // wave-private row q=lm

  f32x4 zero4 = {0.f, 0.f, 0.f, 0.f};
  f32x4 Pacc[4];
#pragma unroll
  for (int i = 0; i < 4; ++i) Pacc[i] = zero4;
  float m_run = -3.0e38f, s_run = 0.0f;

  int it = 0;
  for (;;) {
    const int pb = it & 1;
    if (it) __syncthreads();  // buf[pb] staged; all waves done with buf[1-pb]
    const int nr = rem ? (int)__builtin_ctz(rem) : -1;
    if (nr >= 0) {  // stage next active review (flies under this one's compute)
      const int nbuf = pb ^ 1;
      gload_lds16(kb + ((size_t)(b * 20 + nr) * 64 + srow) * 1024 + h * 64 + scb * 8,
                  kvb0 + nbuf * 16384 + tid * 16);
      gload_lds16(vtg + ((size_t)(b * 20 + nr) * 16 + h) * 4096 + srow * 64 + scb * 8,
                  kvb0 + nbuf * 16384 + 8192 + tid * 16);
    }
    const char* kbse = kvb0 + pb * 16384;
    const char* vbse = kvb0 + pb * 16384 + 8192;

    // ---- S^T = mfma(K, Q): rows t, col q (q pre-scaled by 1/8) ----
    f32x4 sc[4];
#pragma unroll
    for (int i = 0; i < 4; ++i) sc[i] = zero4;
    __builtin_amdgcn_s_setprio(1);
#pragma unroll
    for (int kk = 0; kk < 2; ++kk) {
      bf16x8 kf[4];
#pragma unroll
      for (int i = 0; i < 4; ++i)
        kf[i] = *(const bf16x8*)(kbse + (i * 16 + lm) * 128 + ((kk * 64 + l4 * 16) ^ sw));
#pragma unroll
      for (int i = 0; i < 4; ++i)
        sc[i] = __builtin_amdgcn_mfma_f32_16x16x32_bf16(kf[i], qf[kk], sc[i], 0, 0, 0);
    }
    __builtin_amdgcn_s_setprio(0);

    // ---- token mask (scores already scaled) + softmax over t ----
    const int mbase = (b * 20 + r) * 64;
#pragma unroll
    for (int i = 0; i < 4; ++i) {
      int4 m2 = *(const int4*)(mask2 + mbase + i * 16 + l4 * 4);
      sc[i][0] = (m2.x == 0) ? -1e20f : sc[i][0];
      sc[i][1] = (m2.y == 0) ? -1e20f : sc[i][1];
      sc[i][2] = (m2.z == 0) ? -1e20f : sc[i][2];
      sc[i][3] = (m2.w == 0) ? -1e20f : sc[i][3];
    }
    float mx = sc[0][0];
#pragma unroll
    for (int i = 0; i < 4; ++i)
#pragma unroll
      for (int p = 0; p < 4; ++p) mx = fmaxf(mx, sc[i][p]);
    mx = fmaxf(mx, __shfl_xor(mx, 16));
    mx = fmaxf(mx, __shfl_xor(mx, 32));
    float sum = 0.f;
#pragma unroll
    for (int i = 0; i < 4; ++i)
#pragma unroll
      for (int p = 0; p < 4; ++p) {
        float e = __expf(sc[i][p] - mx);
        sc[i][p] = e;
        sum += e;
      }
    sum += __shfl_xor(sum, 16);
    sum += __shfl_xor(sum, 32);
    const float pinv = __builtin_amdgcn_rcpf(sum);

    // ---- P -> wave-private LDS [q][t], packed 8B swizzled writes ----
#pragma unroll
    for (int i = 0; i < 4; ++i) {
      uint2 wv;
      wv.x = pk2_rhu(sc[i][0] * pinv, sc[i][1] * pinv);
      wv.y = pk2_rhu(sc[i][2] * pinv, sc[i][3] * pinv);
      *(uint2*)(pw + ((i * 32 + l4 * 8) ^ sw)) = wv;
    }

    // ---- att^T = mfma(V^T, P): rows d, col q ----
    f32x4 av[4];
#pragma unroll
    for (int i = 0; i < 4; ++i) av[i] = zero4;
    __builtin_amdgcn_s_setprio(1);
#pragma unroll
    for (int kk = 0; kk < 2; ++kk) {
      bf16x8 pf = *(const bf16x8*)(pw + ((kk * 64 + l4 * 16) ^ sw));
      bf16x8 vf[4];
#pragma unroll
      for (int i = 0; i < 4; ++i)
        vf[i] = *(const bf16x8*)(vbse + (i * 16 + lm) * 128 + ((kk * 64 + l4 * 16) ^ sw));
#pragma unroll
      for (int i = 0; i < 4; ++i)
        av[i] = __builtin_amdgcn_mfma_f32_16x16x32_bf16(vf[i], pf, av[i], 0, 0, 0);
    }
    __builtin_amdgcn_s_setprio(0);

    // ---- att -> same wave-private LDS [q][d] (P already consumed) ----
#pragma unroll
    for (int i = 0; i < 4; ++i) {
      uint2 wv;
      wv.x = pk2_rhu(av[i][0], av[i][1]);
      wv.y = pk2_rhu(av[i][2], av[i][3]);
      *(uint2*)(pw + ((i * 32 + l4 * 8) ^ sw)) = wv;
    }

    // ---- e^T = mfma(sa^T, att): rows jj, col q ----
    f32x4 ep[4];
#pragma unroll
    for (int i = 0; i < 4; ++i) ep[i] = zero4;
    __builtin_amdgcn_s_setprio(1);
#pragma unroll
    for (int kk = 0; kk < 2; ++kk) {
      bf16x8 afr = *(const bf16x8*)(pw + ((kk * 64 + l4 * 16) ^ sw));
#pragma unroll
      for (int i = 0; i < 4; ++i)
        ep[i] = __builtin_amdgcn_mfma_f32_16x16x32_bf16(sfr[kk][i], afr, ep[i], 0, 0, 0);
    }
    __builtin_amdgcn_s_setprio(0);
    float a = 0.f;
#pragma unroll
    for (int i = 0; i < 4; ++i)
#pragma unroll
      for (int p = 0; p < 4; ++p) a += fast_tanh(ep[i][p]) * sbv[i][p];
    a += __shfl_xor(a, 16);
    a += __shfl_xor(a, 32);

    // ---- exact online softmax update over active reviews ----
    // All surviving reviews have add_mask == 0, so e_r = a directly.
    const float e_r = a;
    const float mnew = fmaxf(m_run, e_r);
    const float scl = __expf(m_run - mnew);
    const float w = __expf(e_r - mnew);
    s_run = s_run * scl + w;
#pragma unroll
    for (int i = 0; i < 4; ++i)
#pragma unroll
      for (int p = 0; p < 4; ++p) Pacc[i][p] = Pacc[i][p] * scl + w * av[i][p];
    m_run = mnew;

    if (nr < 0) break;
    r = nr;
    rem &= rem - 1u;
    ++it;
  }

  // ---- merged[b*128+q][h*64+d] = bf16(Pacc / s) ----
  const float inv_s = __builtin_amdgcn_rcpf(s_run);
  unsigned short* mrow = merged + (size_t)(b * 128 + wave * 16 + lm) * 1024 + h * 64;
#pragma unroll
  for (int i = 0; i < 4; ++i) {
    uint2 o;
    o.x = pk2_rhu(Pacc[i][0] * inv_s, Pacc[i][1] * inv_s);
    o.y = pk2_rhu(Pacc[i][2] * inv_s, Pacc[i][3] * inv_s);
    *(uint2*)(mrow + i * 16 + l4 * 4) = o;
  }
}

// ---------------------------------------------------------------------------
extern "C" void kernel_launch(void* const* d_in, const int* in_sizes, int n_in,
                              void* d_out, int out_size, void* d_ws, size_t ws_size,
                              hipStream_t stream) {
  (void)in_sizes; (void)n_in; (void)out_size; (void)ws_size;
  const float* query = (const float*)d_in[0];
  const float* key   = (const float*)d_in[1];
  const float* value = (const float*)d_in[2];
  const int*   mask  = (const int*)d_in[3];
  const int*   mask2 = (const int*)d_in[4];
  const float* Wq = (const float*)d_in[5];
  const float* bq = (const float*)d_in[6];
  const float* Wk = (const float*)d_in[7];
  const float* bk = (const float*)d_in[8];
  const float* Wv = (const float*)d_in[9];
  const float* bv = (const float*)d_in[10];
  const float* Wo = (const float*)d_in[11];
  const float* bo = (const float*)d_in[12];
  const float* sa_a = (const float*)d_in[13];
  const float* sa_b = (const float*)d_in[14];

  char* ws = (char*)d_ws;
  size_t off = 0;
  auto carve = [&](size_t bytes) -> char* {
    char* p = ws + off;
    off += (bytes + 255) & ~(size_t)255;
    return p;
  };
  unsigned short* wq_b = (unsigned short*)carve((size_t)1024 * 1024 * 2);
  unsigned short* wk_b = (unsigned short*)carve((size_t)1024 * 1024 * 2);
  unsigned short* wv_b = (unsigned short*)carve((size_t)1024 * 1024 * 2);
  unsigned short* wo_b = (unsigned short*)carve((size_t)1024 * 1024 * 2);
  unsigned short* q_b  = (unsigned short*)carve((size_t)4096 * 1024 * 2);
  unsigned short* k_b  = (unsigned short*)carve((size_t)40960 * 1024 * 2);
  unsigned short* vt_g = (unsigned short*)carve((size_t)40960 * 1024 * 2);
  unsigned short* mrg  = (unsigned short*)carve((size_t)4096 * 1024 * 2);
  int* cmp = (int*)carve(4096);

  cvt_w4<<<1024, 256, 0, stream>>>(Wq, Wk, Wv, Wo, wq_b, wk_b, wv_b, wo_b);
  compact_rv<<<1, 64, 0, stream>>>(mask, cmp);

  // f32-A direct GEMMs (no cvt_bf16 passes); K/V compacted to active reviews
  gemm_bt<1, 0, 1, 0><<<dim3(32 * 8), 256, 0, stream>>>(query, wq_b, bq, q_b, 1024, 1024, 8, cmp);
  gemm_bt<1, 0, 0, 1><<<dim3(320 * 8), 256, 0, stream>>>(key, wk_b, bk, k_b, 1024, 1024, 8, cmp);
  gemm_bt<2, 0, 0, 1><<<dim3(320 * 8), 256, 0, stream>>>(value, wv_b, bv, vt_g, 1024, 1024, 8, cmp);

  attn2<<<dim3(16, 32), 512, 0, stream>>>(q_b, k_b, vt_g, mask, mask2, sa_a, sa_b, mrg);

  // out projection: A (mrg) is bf16 -> proven bf16-A path
  gemm_bt<0, 1, 0, 0><<<dim3(32 * 8), 256, 0, stream>>>(mrg, wo_b, bo, d_out, 1024, 1024, 8, cmp);
}

// Round 7
// 274.464 us; speedup vs baseline: 2.3060x; 1.1846x over previous
//
#include <hip/hip_runtime.h>
#include <stdint.h>

// ---------------------------------------------------------------------------
// FineReviewDecoderAttention: compact active reviews -> q/k/v proj (f32-A
// direct-staged bf16 MFMA GEMM, counted-vmcnt 2-buffer pipeline + T2 swizzle)
// -> fused attention -> out proj.  B=32 Q=128 D=1024 H=16 d=64 R=20 T=64.
// Delta vs round 19 (passed, 325.1us; K/V gemms 116us, FETCH 327MB = 5x the
// unique active bytes): CMP=1 mapping -> ACTIVE-AWARE CHUNKED XCD SWIZZLE.
// Round-19's plain lg=bx put the 8 blocks sharing an A-tile on 8 different
// XCDs (XCD = bx%8 = nt, proven by round-18's idle-XCD failure) -> every XCD
// streamed the whole active A (~82MB x 8 of L2 fill).  New mapping, computed
// on device from cnt: tiles = ceil(cnt/2); active iff bx < tiles*8;
// lg = (bx&7)*tiles + (bx>>3)  (bijective on [0,tiles*8)).  XCD c owns a
// contiguous lg chunk: consecutive blocks walk nt=0..7 within one mt (A tile
// L2-resident for its 8 consumers), mt covers a contiguous 1/8 slice per XCD
// (A fetched ~once per XCD), W (2MB) L2-resident per XCD.  Expected L2 fill
// ~100MB vs 327MB.  Everything else identical to round 19.
// ---------------------------------------------------------------------------

typedef __attribute__((ext_vector_type(8))) short bf16x8;
typedef __attribute__((ext_vector_type(4))) float f32x4;
typedef __attribute__((ext_vector_type(4))) unsigned int u32x4;
typedef __attribute__((address_space(1))) const unsigned int as1_t;
typedef __attribute__((address_space(3))) unsigned int as3_t;

#define DEVI static __device__ __forceinline__

DEVI unsigned short f2bf(float f) {  // RNE f32->bf16 (finite inputs)
  unsigned int u = __float_as_uint(f);
  u += 0x7fffu + ((u >> 16) & 1u);
  return (unsigned short)(u >> 16);
}
DEVI unsigned int pack2(float a, float b) {
  return (unsigned int)f2bf(a) | ((unsigned int)f2bf(b) << 16);
}
// Round-half-up bf16 pair pack (proven rounds 7-19): a -> lo16, b -> hi16.
DEVI unsigned int pk2_rhu(float a, float b) {
  unsigned int ua = __float_as_uint(a) + 0x8000u;
  unsigned int ub = __float_as_uint(b) + 0x8000u;
  return (ua >> 16) | (ub & 0xffff0000u);
}
// HW packed f32->bf16 (RNE): a -> lo16, b -> hi16.  (round-16-proven)
DEVI unsigned int cvtpk(float a, float b) {
  unsigned int r;
  asm("v_cvt_pk_bf16_f32 %0, %1, %2" : "=v"(r) : "v"(a), "v"(b));
  return r;
}

DEVI bf16x8 u2bf(u32x4 v) {
  union { u32x4 u; bf16x8 b; } c;
  c.u = v;
  return c.b;
}

DEVI void gload_lds16(const void* g, void* l) {
  __builtin_amdgcn_global_load_lds((as1_t*)g, (as3_t*)l, 16, 0, 0);
}

DEVI float fast_tanh(float x) {  // round-5-proven form
  float ax = fabsf(x);
  float e = __expf(2.0f * ax);
  float r = __builtin_fmaf(-2.0f, __builtin_amdgcn_rcpf(e + 1.0f), 1.0f);
  return copysignf(r, x);
}

// ------------------------- weight f32 -> bf16 ------------------------------
__global__ void cvt_w4(const float* __restrict__ w0, const float* __restrict__ w1,
                       const float* __restrict__ w2, const float* __restrict__ w3,
                       unsigned short* __restrict__ o0, unsigned short* __restrict__ o1,
                       unsigned short* __restrict__ o2, unsigned short* __restrict__ o3) {
  int i = blockIdx.x * 256 + threadIdx.x;
  if (i >= 262144) return;
  f32x4 v;
  uint2 a;
  v = ((const f32x4*)w0)[i]; a.x = pack2(v[0], v[1]); a.y = pack2(v[2], v[3]);
  *(uint2*)(o0 + 4 * (size_t)i) = a;
  v = ((const f32x4*)w1)[i]; a.x = pack2(v[0], v[1]); a.y = pack2(v[2], v[3]);
  *(uint2*)(o1 + 4 * (size_t)i) = a;
  v = ((const f32x4*)w2)[i]; a.x = pack2(v[0], v[1]); a.y = pack2(v[2], v[3]);
  *(uint2*)(o2 + 4 * (size_t)i) = a;
  v = ((const f32x4*)w3)[i]; a.x = pack2(v[0], v[1]); a.y = pack2(v[2], v[3]);
  *(uint2*)(o3 + 4 * (size_t)i) = a;
}

// ------------------- active-review slot compaction -------------------------
// out[0] = count; out[1..count] = ascending active slots s = b*20+r;
// out[1+count] = last active slot (pad; used only when count is odd).
// active(s): if batch b has any mask==0 -> (mask[s]==0), else all active.
// Mirrors attn2's bit-exact skip criterion (round-14).
__global__ void compact_rv(const int* __restrict__ mask, int* __restrict__ out) {
  const int lane = (int)threadIdx.x;  // 64 threads, 1 block
  __shared__ int azs[32];
  if (lane < 32) {
    int z = 0;
#pragma unroll
    for (int r = 0; r < 20; ++r) z |= (mask[lane * 20 + r] == 0) ? 1 : 0;
    azs[lane] = z;
  }
  __syncthreads();
  int base = 0;
  int lasts = 0;
  for (int it = 0; it < 10; ++it) {
    const int s = it * 64 + lane;
    const int bb = s / 20;
    const int actv = azs[bb] ? ((mask[s] == 0) ? 1 : 0) : 1;
    unsigned long long bal = __ballot(actv);
    const int off = (int)__popcll(bal & ((1ull << lane) - 1ull));
    if (actv) {
      out[1 + base + off] = s;
      lasts = s;
    }
    base += (int)__popcll(bal);
  }
#pragma unroll
  for (int d = 1; d < 64; d <<= 1) {
    int o = __shfl_xor(lasts, d);
    lasts = lasts > o ? lasts : o;
  }
  if (lane == 0) {
    out[0] = base;
    out[1 + base] = lasts;  // pad for odd count
  }
}

// ---------------- C[m,n] = sum_k A[m,k]*W[n,k] + bias[n] -------------------
// OUT_MODE: 0 = f32 row-major, 1 = bf16 row-major, 2 = bf16 per-head V^T.
// ADT: 0 = A is f32 (direct gload_lds staging, cvt_pk at frag load);
//      1 = A is bf16 (round-12-proven gload_lds path).  SC=1: x0.125.
// CMP=1: M-tiles indirect through compacted active-slot list (64-row slots);
//        active-aware chunked XCD swizzle (see header comment).
template <int OUT_MODE, int ADT, int SC, int CMP>
__global__ __launch_bounds__(256, 4) void gemm_bt(
    const void* __restrict__ Ain, const unsigned short* __restrict__ W,
    const float* __restrict__ bias, void* __restrict__ Cout, int N, int K, int nnt,
    const int* __restrict__ cmp) {
  // ADT=1: A bf16 2x8KB + B 2x8KB = 32KB.
  // ADT=0: A f32 2x16448 (sub1 staggered +64B) + B 2x8KB = 49280B.
  __shared__ __align__(16) char smem[ADT ? 32768 : 49280];
  char* Asb = smem;
  char* Bsb = smem + (ADT ? 16384 : 32896);
  const int ABUF = 16448;  // per-buffer A bytes (ADT=0)
  const int tid = (int)threadIdx.x;
  const int lane = tid & 63, wave = tid >> 6;
  const int lm = lane & 15, l4 = lane >> 4;
  const int nb = (int)gridDim.x;
  const int bx = (int)blockIdx.x;
  const int wr = wave >> 1, wc = wave & 1;

  // ---- tile mapping + M-row slot mapping (64-row slots: cs0, cs1) ----
  int mt, nt, cs0, cs1;
  if (CMP) {
    const int cnt = cmp[0];
    const int tiles = (cnt + 1) >> 1;   // ceil(cnt/2)
    if (bx >= tiles * 8) return;        // uniform exit before any barrier
    // chunked XCD swizzle: XCD (= bx&7, round-robin dispatch) owns a
    // contiguous lg chunk -> nt cycles within one mt, mt slices per XCD.
    const int lg = (bx & 7) * tiles + (bx >> 3);
    mt = lg / nnt;
    nt = lg % nnt;
    cs0 = cmp[1 + 2 * mt];
    cs1 = cmp[2 + 2 * mt];
  } else {
    const int lg = (bx & 7) * (nb >> 3) + (bx >> 3);
    mt = lg / nnt;
    nt = lg % nnt;
    cs0 = 2 * mt;
    cs1 = 2 * mt + 1;
  }

  f32x4 zero4 = {0.f, 0.f, 0.f, 0.f};
  f32x4 acc[4][4];
#pragma unroll
  for (int i = 0; i < 4; ++i)
#pragma unroll
    for (int j = 0; j < 4; ++j) acc[i][j] = zero4;

  // ---- B staging mapping: row = tid>>2, 16B chunk = tid&3.
  // T2 swizzle: chunk (row,blk) lives at slot (row, blk ^ ((row>>1)&3)).
  // Linear LDS dest (tid*16) => pre-swizzle the GLOBAL column: scb.
  const int srow = tid >> 2, sblk = tid & 3;
  const int scb = sblk ^ ((srow >> 1) & 3);
  const unsigned short* wpg = W + (size_t)(nt * 128 + srow) * K + scb * 8;
  // fragment-read XOR key (proven): kx = (lm>>1)&3.
  const int kx = (lm >> 1) & 3;

  if (ADT == 0) {
    // ---- A f32 staging: layout [sub][row][slot], 64B rows, sub1 at +8256
    // (+64B stagger).  Thread stages row tid>>2 of both slots: chunk u=0/1 ->
    // sub0 (K-half 0) rows of cs0/cs1; u=2/3 -> sub1 (K-half 1).
    // Pre-swizzled global column: chunk (tid&3) ^ ((tid>>3)&3).
    const float* apf0 = (const float*)Ain +
                        ((size_t)cs0 * 64 + (tid >> 2)) * K +
                        ((tid & 3) ^ ((tid >> 3) & 3)) * 4;
    const float* apf1 = (const float*)Ain +
                        ((size_t)cs1 * 64 + (tid >> 2)) * K +
                        ((tid & 3) ^ ((tid >> 3) & 3)) * 4;
    const int NT = K >> 5;
#pragma unroll
    for (int t0 = 0; t0 < 2; ++t0) {
      const int kt = t0 * 32;
      gload_lds16(apf0 + kt, Asb + t0 * ABUF + tid * 16);
      gload_lds16(apf1 + kt, Asb + t0 * ABUF + 4096 + tid * 16);
      gload_lds16(apf0 + 16 + kt, Asb + t0 * ABUF + 8256 + tid * 16);
      gload_lds16(apf1 + 16 + kt, Asb + t0 * ABUF + 12352 + tid * 16);
      gload_lds16(wpg + kt, Bsb + t0 * 8192 + tid * 16);
      gload_lds16(wpg + (size_t)64 * K + kt, Bsb + t0 * 8192 + 4096 + tid * 16);
    }
    int cur = 0;
    const int asub = (l4 >> 1) * 8256;  // K-half this lane reads (staggered)
    const int c0r = (l4 & 1) * 2;       // first of 2 global chunks
    const int rd0 = ((c0r ^ kx) * 16);  // swizzled slots
    const int rd1 = (((c0r + 1) ^ kx) * 16);
    for (int t = 0; t < NT; ++t) {
      if (t + 1 < NT)
        asm volatile("s_waitcnt vmcnt(6)" ::: "memory");
      else
        asm volatile("s_waitcnt vmcnt(0)" ::: "memory");
      asm volatile("s_barrier" ::: "memory");
      bf16x8 af[4], bfr[4];
#pragma unroll
      for (int i = 0; i < 4; ++i) {
        const char* ab = Asb + cur * ABUF + asub + (wr * 64 + i * 16 + lm) * 64;
        f32x4 lo = *(const f32x4*)(ab + rd0);
        f32x4 hi = *(const f32x4*)(ab + rd1);
        u32x4 pv = {cvtpk(lo[0], lo[1]), cvtpk(lo[2], lo[3]),
                    cvtpk(hi[0], hi[1]), cvtpk(hi[2], hi[3])};
        af[i] = u2bf(pv);
      }
#pragma unroll
      for (int j = 0; j < 4; ++j)
        bfr[j] = *(const bf16x8*)(Bsb + cur * 8192 + (wc * 64 + j * 16 + lm) * 64 +
                                  ((l4 ^ kx) * 16));
#pragma unroll
      for (int i = 0; i < 4; ++i)
#pragma unroll
        for (int j = 0; j < 4; ++j)
          acc[i][j] = __builtin_amdgcn_mfma_f32_16x16x32_bf16(af[i], bfr[j], acc[i][j], 0, 0, 0);
      asm volatile("s_barrier" ::: "memory");
      if (t + 2 < NT) {
        const int kt = (t + 2) * 32;
        gload_lds16(apf0 + kt, Asb + cur * ABUF + tid * 16);
        gload_lds16(apf1 + kt, Asb + cur * ABUF + 4096 + tid * 16);
        gload_lds16(apf0 + 16 + kt, Asb + cur * ABUF + 8256 + tid * 16);
        gload_lds16(apf1 + 16 + kt, Asb + cur * ABUF + 12352 + tid * 16);
        gload_lds16(wpg + kt, Bsb + cur * 8192 + tid * 16);
        gload_lds16(wpg + (size_t)64 * K + kt, Bsb + cur * 8192 + 4096 + tid * 16);
      }
      cur ^= 1;
    }
  } else {
    // ---- bf16-A path (round-12-proven): counted-vmcnt, swizzled tiles ----
    const unsigned short* apg =
        (const unsigned short*)Ain + (size_t)(mt * 128 + srow) * K + scb * 8;
    const int NT = K >> 5;
#pragma unroll
    for (int t0 = 0; t0 < 2; ++t0) {
      const int kt = t0 * 32;
      gload_lds16(apg + kt, Asb + t0 * 8192 + tid * 16);
      gload_lds16(apg + (size_t)64 * K + kt, Asb + t0 * 8192 + 4096 + tid * 16);
      gload_lds16(wpg + kt, Bsb + t0 * 8192 + tid * 16);
      gload_lds16(wpg + (size_t)64 * K + kt, Bsb + t0 * 8192 + 4096 + tid * 16);
    }
    int cur = 0;
    for (int t = 0; t < NT; ++t) {
      if (t + 1 < NT)
        asm volatile("s_waitcnt vmcnt(4)" ::: "memory");
      else
        asm volatile("s_waitcnt vmcnt(0)" ::: "memory");
      asm volatile("s_barrier" ::: "memory");
      bf16x8 af[4], bfr[4];
#pragma unroll
      for (int i = 0; i < 4; ++i)
        af[i] = *(const bf16x8*)(Asb + cur * 8192 + (wr * 64 + i * 16 + lm) * 64 +
                                 ((l4 ^ kx) * 16));
#pragma unroll
      for (int j = 0; j < 4; ++j)
        bfr[j] = *(const bf16x8*)(Bsb + cur * 8192 + (wc * 64 + j * 16 + lm) * 64 +
                                  ((l4 ^ kx) * 16));
#pragma unroll
      for (int i = 0; i < 4; ++i)
#pragma unroll
        for (int j = 0; j < 4; ++j)
          acc[i][j] = __builtin_amdgcn_mfma_f32_16x16x32_bf16(af[i], bfr[j], acc[i][j], 0, 0, 0);
      asm volatile("s_barrier" ::: "memory");
      if (t + 2 < NT) {
        const int kt = (t + 2) * 32;
        gload_lds16(apg + kt, Asb + cur * 8192 + tid * 16);
        gload_lds16(apg + (size_t)64 * K + kt, Asb + cur * 8192 + 4096 + tid * 16);
        gload_lds16(wpg + kt, Bsb + cur * 8192 + tid * 16);
        gload_lds16(wpg + (size_t)64 * K + kt, Bsb + cur * 8192 + 4096 + tid * 16);
      }
      cur ^= 1;
    }
  }

  const int c0o = nt * 128 + wc * 64 + lm;
  float bb[4];
#pragma unroll
  for (int j = 0; j < 4; ++j) bb[j] = bias[c0o + j * 16];
  const int mslot = wr ? cs1 : cs0;  // this wave's 64-row slot

  if (OUT_MODE < 2) {
#pragma unroll
    for (int i = 0; i < 4; ++i)
#pragma unroll
      for (int j = 0; j < 4; ++j)
#pragma unroll
        for (int p = 0; p < 4; ++p) {
          size_t grow = (size_t)mslot * 64 + (l4 * 4 + i * 16 + p);
          size_t idx = grow * N + (size_t)(c0o + j * 16);
          float v = acc[i][j][p] + bb[j];
          if (SC) v *= 0.125f;  // exact exponent shift; bf16(v/8) == bf16(v)/8
          if (OUT_MODE == 1)
            ((unsigned short*)Cout)[idx] = f2bf(v);
          else
            ((float*)Cout)[idx] = v;
        }
  } else {
    // V^T per-head tiles: vt[(slot*16+h)*4096 + d*64 + t], t = i*16+l4*4+p
    const int hh = (nt * 128 + wc * 64) / 64;
    unsigned short* vt = (unsigned short*)Cout;
    const size_t base = ((size_t)mslot * 16 + hh) * 4096;
#pragma unroll
    for (int j = 0; j < 4; ++j) {
      const int d = lm + j * 16;
#pragma unroll
      for (int i = 0; i < 4; ++i) {
        uint2 wv;
        wv.x = pack2(acc[i][j][0] + bb[j], acc[i][j][1] + bb[j]);
        wv.y = pack2(acc[i][j][2] + bb[j], acc[i][j][3] + bb[j]);
        *(uint2*)(vt + base + (size_t)d * 64 + i * 16 + l4 * 4) = wv;
      }
    }
  }
}

// ----------------------------- fused attention -----------------------------
// One block per (h, b); 8 waves, wave w owns q rows [16w,16w+16).
// Swapped-operand MFMAs so q = lane&15 everywhere; online softmax over r.
// LDS (48KB): kv_s[2][K,V] 32KB; pa_s 16KB; q/sa^T staging overlays.
// Active-review compaction: reviews with mask==1 (when any mask==0 exists in
// row b) have pooled weight exactly 0.0f (expf(-1e30 - max) underflows) ->
// skipped entirely.  Bitmask is uniform per block (depends only on b).
__global__ __launch_bounds__(512, 4) void attn2(
    const unsigned short* __restrict__ qb, const unsigned short* __restrict__ kb,
    const unsigned short* __restrict__ vtg, const int* __restrict__ mask,
    const int* __restrict__ mask2, const float* __restrict__ sa_a,
    const float* __restrict__ sa_b, unsigned short* __restrict__ merged) {
  const int h = (int)blockIdx.x;
  const int b = (int)blockIdx.y;
  const int tid = (int)threadIdx.x;
  const int lane = tid & 63, wave = tid >> 6;
  const int lm = lane & 15, l4 = lane >> 4;
  const int sw = (lm & 7) << 4;

  __shared__ unsigned short kv_s[2][2][64 * 64];  // [buf][0=K [t][d], 1=V^T [d][t]]
  __shared__ unsigned short pa_s[8 * 16 * 64];    // wave-private P/att rows

  char* kvb0 = (char*)kv_s;          // buf stride 16384; V^T at +8192
  char* qreg = (char*)kv_s + 16384;  // q staging region = buf1 (dead after hoist)
  char* satb = (char*)pa_s;          // sa^T staging (dead after hoist)

  // ---- active-review bitmask (uniform across the block) ----
  unsigned am = 0u;
#pragma unroll
  for (int rr = 0; rr < 20; ++rr)
    am |= (mask[b * 20 + rr] == 0) ? (1u << rr) : 0u;
  // az (= some review has mask==0) => only those reviews survive; else all.
  const unsigned act = am ? am : 0xFFFFFu;

  // ---- stage Q into qreg (pre-swizzled source columns) ----
#pragma unroll
  for (int s = 0; s < 2; ++s) {
    int idx = s * 512 + tid, row = idx >> 3, blk = idx & 7;
    int cb = blk ^ (row & 7);
    gload_lds16(qb + (size_t)(b * 128 + row) * 1024 + h * 64 + cb * 8, qreg + idx * 16);
  }
  // ---- stage sa^T into satb: sat[jj][d] = sa_a[d][jj], swizzled ----
#pragma unroll
  for (int s = 0; s < 8; ++s) {
    int idx = s * 512 + tid, jj = idx & 63, d = idx >> 6;
    *(unsigned short*)(satb + jj * 128 + ((d * 2) ^ ((jj & 7) << 4))) =
        f2bf(sa_a[d * 64 + jj]);
  }
  // ---- stage first ACTIVE review K/V into buf0 ----
  const int srow = tid >> 3, sblk = tid & 7;
  const int scb = sblk ^ (srow & 7);
  int r = (int)__builtin_ctz(act);
  unsigned rem = act & (act - 1u);
  gload_lds16(kb + ((size_t)(b * 20 + r) * 64 + srow) * 1024 + h * 64 + scb * 8,
              kvb0 + tid * 16);
  gload_lds16(vtg + ((size_t)(b * 20 + r) * 16 + h) * 4096 + srow * 64 + scb * 8,
              kvb0 + 8192 + tid * 16);

  f32x4 sbv[4];
#pragma unroll
  for (int i = 0; i < 4; ++i) sbv[i] = *(const f32x4*)(sa_b + i * 16 + l4 * 4);

  __syncthreads();  // qreg, satb, buf0 all visible

  // ---- hoist Q B-fragments and sa^T A-fragments to registers ----
  const char* qrp = qreg + (wave * 16 + lm) * 128;
  bf16x8 qf[2];
  qf[0] = *(const bf16x8*)(qrp + ((l4 * 16) ^ sw));
  qf[1] = *(const bf16x8*)(qrp + ((64 + l4 * 16) ^ sw));
  bf16x8 sfr[2][4];
#pragma unroll
  for (int kk = 0; kk < 2; ++kk)
#pragma unroll
    for (int i = 0; i < 4; ++i)
      sfr[kk][i] = *(const bf16x8*)(satb + (i * 16 + lm) * 128 +
                                    ((kk * 64 + l4 * 16) ^ sw));
  asm volatile("s_waitcnt lgkmcnt(0)" ::: "memory");  // hoist reads retired
  __syncthreads();  // all waves done -> qreg/satb reusable as buf1 / P-rows

  char* pw = (char*)pa_s + wave * 2048 + lm * 128;  // wave-private row q=lm

  f32x4 zero4 = {0.f, 0.f, 0.f, 0.f};
  f32x4 Pacc[4];
#pragma unroll
  for (int i = 0; i < 4; ++i) Pacc[i] = zero4;
  float m_run = -3.0e38f, s_run = 0.0f;

  int it = 0;
  for (;;) {
    const int pb = it & 1;
    if (it) __syncthreads();  // buf[pb] staged; all waves done with buf[1-pb]
    const int nr = rem ? (int)__builtin_ctz(rem) : -1;
    if (nr >= 0) {  // stage next active review (flies under this one's compute)
      const int nbuf = pb ^ 1;
      gload_lds16(kb + ((size_t)(b * 20 + nr) * 64 + srow) * 1024 + h * 64 + scb * 8,
                  kvb0 + nbuf * 16384 + tid * 16);
      gload_lds16(vtg + ((size_t)(b * 20 + nr) * 16 + h) * 4096 + srow * 64 + scb * 8,
                  kvb0 + nbuf * 16384 + 8192 + tid * 16);
    }
    const char* kbse = kvb0 + pb * 16384;
    const char* vbse = kvb0 + pb * 16384 + 8192;

    // ---- S^T = mfma(K, Q): rows t, col q (q pre-scaled by 1/8) ----
    f32x4 sc[4];
#pragma unroll
    for (int i = 0; i < 4; ++i) sc[i] = zero4;
    __builtin_amdgcn_s_setprio(1);
#pragma unroll
    for (int kk = 0; kk < 2; ++kk) {
      bf16x8 kf[4];
#pragma unroll
      for (int i = 0; i < 4; ++i)
        kf[i] = *(const bf16x8*)(kbse + (i * 16 + lm) * 128 + ((kk * 64 + l4 * 16) ^ sw));
#pragma unroll
      for (int i = 0; i < 4; ++i)
        sc[i] = __builtin_amdgcn_mfma_f32_16x16x32_bf16(kf[i], qf[kk], sc[i], 0, 0, 0);
    }
    __builtin_amdgcn_s_setprio(0);

    // ---- token mask (scores already scaled) + softmax over t ----
    const int mbase = (b * 20 + r) * 64;
#pragma unroll
    for (int i = 0; i < 4; ++i) {
      int4 m2 = *(const int4*)(mask2 + mbase + i * 16 + l4 * 4);
      sc[i][0] = (m2.x == 0) ? -1e20f : sc[i][0];
      sc[i][1] = (m2.y == 0) ? -1e20f : sc[i][1];
      sc[i][2] = (m2.z == 0) ? -1e20f : sc[i][2];
      sc[i][3] = (m2.w == 0) ? -1e20f : sc[i][3];
    }
    float mx = sc[0][0];
#pragma unroll
    for (int i = 0; i < 4; ++i)
#pragma unroll
      for (int p = 0; p < 4; ++p) mx = fmaxf(mx, sc[i][p]);
    mx = fmaxf(mx, __shfl_xor(mx, 16));
    mx = fmaxf(mx, __shfl_xor(mx, 32));
    float sum = 0.f;
#pragma unroll
    for (int i = 0; i < 4; ++i)
#pragma unroll
      for (int p = 0; p < 4; ++p) {
        float e = __expf(sc[i][p] - mx);
        sc[i][p] = e;
        sum += e;
      }
    sum += __shfl_xor(sum, 16);
    sum += __shfl_xor(sum, 32);
    const float pinv = __builtin_amdgcn_rcpf(sum);

    // ---- P -> wave-private LDS [q][t], packed 8B swizzled writes ----
#pragma unroll
    for (int i = 0; i < 4; ++i) {
      uint2 wv;
      wv.x = pk2_rhu(sc[i][0] * pinv, sc[i][1] * pinv);
      wv.y = pk2_rhu(sc[i][2] * pinv, sc[i][3] * pinv);
      *(uint2*)(pw + ((i * 32 + l4 * 8) ^ sw)) = wv;
    }

    // ---- att^T = mfma(V^T, P): rows d, col q ----
    f32x4 av[4];
#pragma unroll
    for (int i = 0; i < 4; ++i) av[i] = zero4;
    __builtin_amdgcn_s_setprio(1);
#pragma unroll
    for (int kk = 0; kk < 2; ++kk) {
      bf16x8 pf = *(const bf16x8*)(pw + ((kk * 64 + l4 * 16) ^ sw));
      bf16x8 vf[4];
#pragma unroll
      for (int i = 0; i < 4; ++i)
        vf[i] = *(const bf16x8*)(vbse + (i * 16 + lm) * 128 + ((kk * 64 + l4 * 16) ^ sw));
#pragma unroll
      for (int i = 0; i < 4; ++i)
        av[i] = __builtin_amdgcn_mfma_f32_16x16x32_bf16(vf[i], pf, av[i], 0, 0, 0);
    }
    __builtin_amdgcn_s_setprio(0);

    // ---- att -> same wave-private LDS [q][d] (P already consumed) ----
#pragma unroll
    for (int i = 0; i < 4; ++i) {
      uint2 wv;
      wv.x = pk2_rhu(av[i][0], av[i][1]);
      wv.y = pk2_rhu(av[i][2], av[i][3]);
      *(uint2*)(pw + ((i * 32 + l4 * 8) ^ sw)) = wv;
    }

    // ---- e^T = mfma(sa^T, att): rows jj, col q ----
    f32x4 ep[4];
#pragma unroll
    for (int i = 0; i < 4; ++i) ep[i] = zero4;
    __builtin_amdgcn_s_setprio(1);
#pragma unroll
    for (int kk = 0; kk < 2; ++kk) {
      bf16x8 afr = *(const bf16x8*)(pw + ((kk * 64 + l4 * 16) ^ sw));
#pragma unroll
      for (int i = 0; i < 4; ++i)
        ep[i] = __builtin_amdgcn_mfma_f32_16x16x32_bf16(sfr[kk][i], afr, ep[i], 0, 0, 0);
    }
    __builtin_amdgcn_s_setprio(0);
    float a = 0.f;
#pragma unroll
    for (int i = 0; i < 4; ++i)
#pragma unroll
      for (int p = 0; p < 4; ++p) a += fast_tanh(ep[i][p]) * sbv[i][p];
    a += __shfl_xor(a, 16);
    a += __shfl_xor(a, 32);

    // ---- exact online softmax update over active reviews ----
    // All surviving reviews have add_mask == 0, so e_r = a directly.
    const float e_r = a;
    const float mnew = fmaxf(m_run, e_r);
    const float scl = __expf(m_run - mnew);
    const float w = __expf(e_r - mnew);
    s_run = s_run * scl + w;
#pragma unroll
    for (int i = 0; i < 4; ++i)
#pragma unroll
      for (int p = 0; p < 4; ++p) Pacc[i][p] = Pacc[i][p] * scl + w * av[i][p];
    m_run = mnew;

    if (nr < 0) break;
    r = nr;
    rem &= rem - 1u;
    ++it;
  }

  // ---- merged[b*128+q][h*64+d] = bf16(Pacc / s) ----
  const float inv_s = __builtin_amdgcn_rcpf(s_run);
  unsigned short* mrow = merged + (size_t)(b * 128 + wave * 16 + lm) * 1024 + h * 64;
#pragma unroll
  for (int i = 0; i < 4; ++i) {
    uint2 o;
    o.x = pk2_rhu(Pacc[i][0] * inv_s, Pacc[i][1] * inv_s);
    o.y = pk2_rhu(Pacc[i][2] * inv_s, Pacc[i][3] * inv_s);
    *(uint2*)(mrow + i * 16 + l4 * 4) = o;
  }
}

// ---------------------------------------------------------------------------
extern "C" void kernel_launch(void* const* d_in, const int* in_sizes, int n_in,
                              void* d_out, int out_size, void* d_ws, size_t ws_size,
                              hipStream_t stream) {
  (void)in_sizes; (void)n_in; (void)out_size; (void)ws_size;
  const float* query = (const float*)d_in[0];
  const float* key   = (const float*)d_in[1];
  const float* value = (const float*)d_in[2];
  const int*   mask  = (const int*)d_in[3];
  const int*   mask2 = (const int*)d_in[4];
  const float* Wq = (const float*)d_in[5];
  const float* bq = (const float*)d_in[6];
  const float* Wk = (const float*)d_in[7];
  const float* bk = (const float*)d_in[8];
  const float* Wv = (const float*)d_in[9];
  const float* bv = (const float*)d_in[10];
  const float* Wo = (const float*)d_in[11];
  const float* bo = (const float*)d_in[12];
  const float* sa_a = (const float*)d_in[13];
  const float* sa_b = (const float*)d_in[14];

  char* ws = (char*)d_ws;
  size_t off = 0;
  auto carve = [&](size_t bytes) -> char* {
    char* p = ws + off;
    off += (bytes + 255) & ~(size_t)255;
    return p;
  };
  unsigned short* wq_b = (unsigned short*)carve((size_t)1024 * 1024 * 2);
  unsigned short* wk_b = (unsigned short*)carve((size_t)1024 * 1024 * 2);
  unsigned short* wv_b = (unsigned short*)carve((size_t)1024 * 1024 * 2);
  unsigned short* wo_b = (unsigned short*)carve((size_t)1024 * 1024 * 2);
  unsigned short* q_b  = (unsigned short*)carve((size_t)4096 * 1024 * 2);
  unsigned short* k_b  = (unsigned short*)carve((size_t)40960 * 1024 * 2);
  unsigned short* vt_g = (unsigned short*)carve((size_t)40960 * 1024 * 2);
  unsigned short* mrg  = (unsigned short*)carve((size_t)4096 * 1024 * 2);
  int* cmp = (int*)carve(4096);

  cvt_w4<<<1024, 256, 0, stream>>>(Wq, Wk, Wv, Wo, wq_b, wk_b, wv_b, wo_b);
  compact_rv<<<1, 64, 0, stream>>>(mask, cmp);

  // f32-A direct GEMMs (no cvt_bf16 passes); K/V compacted to active reviews
  gemm_bt<1, 0, 1, 0><<<dim3(32 * 8), 256, 0, stream>>>(query, wq_b, bq, q_b, 1024, 1024, 8, cmp);
  gemm_bt<1, 0, 0, 1><<<dim3(320 * 8), 256, 0, stream>>>(key, wk_b, bk, k_b, 1024, 1024, 8, cmp);
  gemm_bt<2, 0, 0, 1><<<dim3(320 * 8), 256, 0, stream>>>(value, wv_b, bv, vt_g, 1024, 1024, 8, cmp);

  attn2<<<dim3(16, 32), 512, 0, stream>>>(q_b, k_b, vt_g, mask, mask2, sa_a, sa_b, mrg);

  // out projection: A (mrg) is bf16 -> proven bf16-A path
  gemm_bt<0, 1, 0, 0><<<dim3(32 * 8), 256, 0, stream>>>(mrg, wo_b, bo, d_out, 1024, 1024, 8, cmp);
}

// Round 8
// 269.250 us; speedup vs baseline: 2.3506x; 1.0194x over previous
//
#include <hip/hip_runtime.h>
#include <stdint.h>

// ---------------------------------------------------------------------------
// FineReviewDecoderAttention: compact active reviews -> compacted cvt f32->
// bf16 for K/V -> q/k/v proj (bf16 MFMA GEMM, counted-vmcnt 2-buffer
// pipeline + proven T2 swizzle, chunked XCD swizzle for compacted grids) ->
// fused attention -> out proj.  B=32 Q=128 D=1024 H=16 d=64 R=20 T=64.
// Delta vs round 20 (passed, 274.5us): K/V GEMMs moved OFF the f32-direct A
// path (404 TF, 4096 conflicts/block across 3 layout attempts, 49.7KB LDS ->
// 3 blocks/CU) and back onto the round-1-PROVEN bf16 ADT=1 path (728 TF
// measured, 0 conflicts, 32KB LDS), fed by a compacted cvt_act pass that
// converts ONLY active slots (pack2 RNE = bit-identical MFMA inputs) into a
// dense buffer.  Dense A indexing by mt; C-writes stay at absolute slots via
// cmp; odd-count pad slot is converted too (cmp[1+cnt]) so the pad tile
// reads valid data.  One 80MB act buffer reused K-then-V (ws ~264MB, the
// footprint proven available by round 1's fat path).  Q-proj stays
// f32-direct (small); out-proj / attn2 unchanged.
// ---------------------------------------------------------------------------

typedef __attribute__((ext_vector_type(8))) short bf16x8;
typedef __attribute__((ext_vector_type(4))) float f32x4;
typedef __attribute__((ext_vector_type(4))) unsigned int u32x4;
typedef __attribute__((address_space(1))) const unsigned int as1_t;
typedef __attribute__((address_space(3))) unsigned int as3_t;

#define DEVI static __device__ __forceinline__

DEVI unsigned short f2bf(float f) {  // RNE f32->bf16 (finite inputs)
  unsigned int u = __float_as_uint(f);
  u += 0x7fffu + ((u >> 16) & 1u);
  return (unsigned short)(u >> 16);
}
DEVI unsigned int pack2(float a, float b) {
  return (unsigned int)f2bf(a) | ((unsigned int)f2bf(b) << 16);
}
// Round-half-up bf16 pair pack (proven rounds 7-20): a -> lo16, b -> hi16.
DEVI unsigned int pk2_rhu(float a, float b) {
  unsigned int ua = __float_as_uint(a) + 0x8000u;
  unsigned int ub = __float_as_uint(b) + 0x8000u;
  return (ua >> 16) | (ub & 0xffff0000u);
}
// HW packed f32->bf16 (RNE): a -> lo16, b -> hi16.  (round-16-proven)
DEVI unsigned int cvtpk(float a, float b) {
  unsigned int r;
  asm("v_cvt_pk_bf16_f32 %0, %1, %2" : "=v"(r) : "v"(a), "v"(b));
  return r;
}

DEVI bf16x8 u2bf(u32x4 v) {
  union { u32x4 u; bf16x8 b; } c;
  c.u = v;
  return c.b;
}

DEVI void gload_lds16(const void* g, void* l) {
  __builtin_amdgcn_global_load_lds((as1_t*)g, (as3_t*)l, 16, 0, 0);
}

DEVI float fast_tanh(float x) {  // round-5-proven form
  float ax = fabsf(x);
  float e = __expf(2.0f * ax);
  float r = __builtin_fmaf(-2.0f, __builtin_amdgcn_rcpf(e + 1.0f), 1.0f);
  return copysignf(r, x);
}

// ------------------------- weight f32 -> bf16 ------------------------------
__global__ void cvt_w4(const float* __restrict__ w0, const float* __restrict__ w1,
                       const float* __restrict__ w2, const float* __restrict__ w3,
                       unsigned short* __restrict__ o0, unsigned short* __restrict__ o1,
                       unsigned short* __restrict__ o2, unsigned short* __restrict__ o3) {
  int i = blockIdx.x * 256 + threadIdx.x;
  if (i >= 262144) return;
  f32x4 v;
  uint2 a;
  v = ((const f32x4*)w0)[i]; a.x = pack2(v[0], v[1]); a.y = pack2(v[2], v[3]);
  *(uint2*)(o0 + 4 * (size_t)i) = a;
  v = ((const f32x4*)w1)[i]; a.x = pack2(v[0], v[1]); a.y = pack2(v[2], v[3]);
  *(uint2*)(o1 + 4 * (size_t)i) = a;
  v = ((const f32x4*)w2)[i]; a.x = pack2(v[0], v[1]); a.y = pack2(v[2], v[3]);
  *(uint2*)(o2 + 4 * (size_t)i) = a;
  v = ((const f32x4*)w3)[i]; a.x = pack2(v[0], v[1]); a.y = pack2(v[2], v[3]);
  *(uint2*)(o3 + 4 * (size_t)i) = a;
}

// ------------------- active-review slot compaction -------------------------
// out[0] = count; out[1..count] = ascending active slots s = b*20+r;
// out[1+count] = last active slot (pad; used only when count is odd).
// active(s): if batch b has any mask==0 -> (mask[s]==0), else all active.
// Mirrors attn2's bit-exact skip criterion (round-14).
__global__ void compact_rv(const int* __restrict__ mask, int* __restrict__ out) {
  const int lane = (int)threadIdx.x;  // 64 threads, 1 block
  __shared__ int azs[32];
  if (lane < 32) {
    int z = 0;
#pragma unroll
    for (int r = 0; r < 20; ++r) z |= (mask[lane * 20 + r] == 0) ? 1 : 0;
    azs[lane] = z;
  }
  __syncthreads();
  int base = 0;
  int lasts = 0;
  for (int it = 0; it < 10; ++it) {
    const int s = it * 64 + lane;
    const int bb = s / 20;
    const int actv = azs[bb] ? ((mask[s] == 0) ? 1 : 0) : 1;
    unsigned long long bal = __ballot(actv);
    const int off = (int)__popcll(bal & ((1ull << lane) - 1ull));
    if (actv) {
      out[1 + base + off] = s;
      lasts = s;
    }
    base += (int)__popcll(bal);
  }
#pragma unroll
  for (int d = 1; d < 64; d <<= 1) {
    int o = __shfl_xor(lasts, d);
    lasts = lasts > o ? lasts : o;
  }
  if (lane == 0) {
    out[0] = base;
    out[1 + base] = lasts;  // pad for odd count
  }
}

// --------------- compacted activation f32 -> bf16 (active slots) -----------
// dst is DENSE: compact position s holds slot cmp[1+s].  Converts
// round_up_even(cnt) slots so the odd-count pad tile reads valid data.
// Unit = 8 elements; slot = 64 rows x 1024 cols = 8192 units.
__global__ void cvt_act(const float* __restrict__ src,
                        unsigned short* __restrict__ dst,
                        const int* __restrict__ cmp) {
  const int cnt = cmp[0];
  const int n = ((cnt + 1) & ~1) * 8192;
  const int stride = (int)(gridDim.x * blockDim.x);
  for (int u = (int)(blockIdx.x * blockDim.x + threadIdx.x); u < n; u += stride) {
    const int s = u >> 13;
    const int e = u & 8191;
    const size_t so = (size_t)cmp[1 + s] * 65536 + (size_t)e * 8;
    f32x4 a = *(const f32x4*)(src + so);
    f32x4 b = *(const f32x4*)(src + so + 4);
    u32x4 o = {pack2(a[0], a[1]), pack2(a[2], a[3]),
               pack2(b[0], b[1]), pack2(b[2], b[3])};
    *(u32x4*)(dst + (size_t)u * 8) = o;
  }
}

// ---------------- C[m,n] = sum_k A[m,k]*W[n,k] + bias[n] -------------------
// OUT_MODE: 0 = f32 row-major, 1 = bf16 row-major, 2 = bf16 per-head V^T.
// ADT: 0 = A is f32 (direct gload_lds staging, cvt_pk at frag load);
//      1 = A is bf16 (round-12-proven gload_lds path).  SC=1: x0.125.
// CMP=1: A is DENSE-compacted (indexed by mt); C-writes go to absolute
//        slots cs0/cs1 from cmp; active-aware chunked XCD swizzle; blocks
//        beyond the active count exit early (uniform).
template <int OUT_MODE, int ADT, int SC, int CMP>
__global__ __launch_bounds__(256, 4) void gemm_bt(
    const void* __restrict__ Ain, const unsigned short* __restrict__ W,
    const float* __restrict__ bias, void* __restrict__ Cout, int N, int K, int nnt,
    const int* __restrict__ cmp) {
  // ADT=1: A bf16 2x8KB + B 2x8KB = 32KB.
  // ADT=0: A f32 2x16448 (sub1 staggered +64B) + B 2x8KB = 49280B.
  __shared__ __align__(16) char smem[ADT ? 32768 : 49280];
  char* Asb = smem;
  char* Bsb = smem + (ADT ? 16384 : 32896);
  const int ABUF = 16448;  // per-buffer A bytes (ADT=0)
  const int tid = (int)threadIdx.x;
  const int lane = tid & 63, wave = tid >> 6;
  const int lm = lane & 15, l4 = lane >> 4;
  const int nb = (int)gridDim.x;
  const int bx = (int)blockIdx.x;
  const int wr = wave >> 1, wc = wave & 1;

  // ---- tile mapping + output slot mapping (64-row slots: cs0, cs1) ----
  int mt, nt, cs0, cs1;
  if (CMP) {
    const int cnt = cmp[0];
    const int tiles = (cnt + 1) >> 1;   // ceil(cnt/2)
    if (bx >= tiles * 8) return;        // uniform exit before any barrier
    // chunked XCD swizzle (round-20-proven): XCD (= bx&7) owns a contiguous
    // lg chunk -> nt cycles within one mt, mt slices per XCD.
    const int lg = (bx & 7) * tiles + (bx >> 3);
    mt = lg / nnt;
    nt = lg % nnt;
    cs0 = cmp[1 + 2 * mt];
    cs1 = cmp[2 + 2 * mt];
  } else {
    const int lg = (bx & 7) * (nb >> 3) + (bx >> 3);
    mt = lg / nnt;
    nt = lg % nnt;
    cs0 = 2 * mt;
    cs1 = 2 * mt + 1;
  }

  f32x4 zero4 = {0.f, 0.f, 0.f, 0.f};
  f32x4 acc[4][4];
#pragma unroll
  for (int i = 0; i < 4; ++i)
#pragma unroll
    for (int j = 0; j < 4; ++j) acc[i][j] = zero4;

  // ---- B staging mapping: row = tid>>2, 16B chunk = tid&3.
  // T2 swizzle: chunk (row,blk) lives at slot (row, blk ^ ((row>>1)&3)).
  // Linear LDS dest (tid*16) => pre-swizzle the GLOBAL column: scb.
  const int srow = tid >> 2, sblk = tid & 3;
  const int scb = sblk ^ ((srow >> 1) & 3);
  const unsigned short* wpg = W + (size_t)(nt * 128 + srow) * K + scb * 8;
  // fragment-read XOR key (proven): kx = (lm>>1)&3.
  const int kx = (lm >> 1) & 3;

  if (ADT == 0) {
    // ---- A f32 staging (round-18-proven): [sub][row][slot], 64B rows,
    // sub1 at +8256.  Thread stages row tid>>2 of both slots.
    const float* apf0 = (const float*)Ain +
                        ((size_t)cs0 * 64 + (tid >> 2)) * K +
                        ((tid & 3) ^ ((tid >> 3) & 3)) * 4;
    const float* apf1 = (const float*)Ain +
                        ((size_t)cs1 * 64 + (tid >> 2)) * K +
                        ((tid & 3) ^ ((tid >> 3) & 3)) * 4;
    const int NT = K >> 5;
#pragma unroll
    for (int t0 = 0; t0 < 2; ++t0) {
      const int kt = t0 * 32;
      gload_lds16(apf0 + kt, Asb + t0 * ABUF + tid * 16);
      gload_lds16(apf1 + kt, Asb + t0 * ABUF + 4096 + tid * 16);
      gload_lds16(apf0 + 16 + kt, Asb + t0 * ABUF + 8256 + tid * 16);
      gload_lds16(apf1 + 16 + kt, Asb + t0 * ABUF + 12352 + tid * 16);
      gload_lds16(wpg + kt, Bsb + t0 * 8192 + tid * 16);
      gload_lds16(wpg + (size_t)64 * K + kt, Bsb + t0 * 8192 + 4096 + tid * 16);
    }
    int cur = 0;
    const int asub = (l4 >> 1) * 8256;  // K-half this lane reads (staggered)
    const int c0r = (l4 & 1) * 2;       // first of 2 global chunks
    const int rd0 = ((c0r ^ kx) * 16);  // swizzled slots
    const int rd1 = (((c0r + 1) ^ kx) * 16);
    for (int t = 0; t < NT; ++t) {
      if (t + 1 < NT)
        asm volatile("s_waitcnt vmcnt(6)" ::: "memory");
      else
        asm volatile("s_waitcnt vmcnt(0)" ::: "memory");
      asm volatile("s_barrier" ::: "memory");
      bf16x8 af[4], bfr[4];
#pragma unroll
      for (int i = 0; i < 4; ++i) {
        const char* ab = Asb + cur * ABUF + asub + (wr * 64 + i * 16 + lm) * 64;
        f32x4 lo = *(const f32x4*)(ab + rd0);
        f32x4 hi = *(const f32x4*)(ab + rd1);
        u32x4 pv = {cvtpk(lo[0], lo[1]), cvtpk(lo[2], lo[3]),
                    cvtpk(hi[0], hi[1]), cvtpk(hi[2], hi[3])};
        af[i] = u2bf(pv);
      }
#pragma unroll
      for (int j = 0; j < 4; ++j)
        bfr[j] = *(const bf16x8*)(Bsb + cur * 8192 + (wc * 64 + j * 16 + lm) * 64 +
                                  ((l4 ^ kx) * 16));
#pragma unroll
      for (int i = 0; i < 4; ++i)
#pragma unroll
        for (int j = 0; j < 4; ++j)
          acc[i][j] = __builtin_amdgcn_mfma_f32_16x16x32_bf16(af[i], bfr[j], acc[i][j], 0, 0, 0);
      asm volatile("s_barrier" ::: "memory");
      if (t + 2 < NT) {
        const int kt = (t + 2) * 32;
        gload_lds16(apf0 + kt, Asb + cur * ABUF + tid * 16);
        gload_lds16(apf1 + kt, Asb + cur * ABUF + 4096 + tid * 16);
        gload_lds16(apf0 + 16 + kt, Asb + cur * ABUF + 8256 + tid * 16);
        gload_lds16(apf1 + 16 + kt, Asb + cur * ABUF + 12352 + tid * 16);
        gload_lds16(wpg + kt, Bsb + cur * 8192 + tid * 16);
        gload_lds16(wpg + (size_t)64 * K + kt, Bsb + cur * 8192 + 4096 + tid * 16);
      }
      cur ^= 1;
    }
  } else {
    // ---- bf16-A path (round-12-proven): counted-vmcnt, swizzled tiles.
    // CMP=1: A is dense-compacted -> index by mt directly.
    const unsigned short* apg =
        (const unsigned short*)Ain + (size_t)(mt * 128 + srow) * K + scb * 8;
    const int NT = K >> 5;
#pragma unroll
    for (int t0 = 0; t0 < 2; ++t0) {
      const int kt = t0 * 32;
      gload_lds16(apg + kt, Asb + t0 * 8192 + tid * 16);
      gload_lds16(apg + (size_t)64 * K + kt, Asb + t0 * 8192 + 4096 + tid * 16);
      gload_lds16(wpg + kt, Bsb + t0 * 8192 + tid * 16);
      gload_lds16(wpg + (size_t)64 * K + kt, Bsb + t0 * 8192 + 4096 + tid * 16);
    }
    int cur = 0;
    for (int t = 0; t < NT; ++t) {
      if (t + 1 < NT)
        asm volatile("s_waitcnt vmcnt(4)" ::: "memory");
      else
        asm volatile("s_waitcnt vmcnt(0)" ::: "memory");
      asm volatile("s_barrier" ::: "memory");
      bf16x8 af[4], bfr[4];
#pragma unroll
      for (int i = 0; i < 4; ++i)
        af[i] = *(const bf16x8*)(Asb + cur * 8192 + (wr * 64 + i * 16 + lm) * 64 +
                                 ((l4 ^ kx) * 16));
#pragma unroll
      for (int j = 0; j < 4; ++j)
        bfr[j] = *(const bf16x8*)(Bsb + cur * 8192 + (wc * 64 + j * 16 + lm) * 64 +
                                  ((l4 ^ kx) * 16));
#pragma unroll
      for (int i = 0; i < 4; ++i)
#pragma unroll
        for (int j = 0; j < 4; ++j)
          acc[i][j] = __builtin_amdgcn_mfma_f32_16x16x32_bf16(af[i], bfr[j], acc[i][j], 0, 0, 0);
      asm volatile("s_barrier" ::: "memory");
      if (t + 2 < NT) {
        const int kt = (t + 2) * 32;
        gload_lds16(apg + kt, Asb + cur * 8192 + tid * 16);
        gload_lds16(apg + (size_t)64 * K + kt, Asb + cur * 8192 + 4096 + tid * 16);
        gload_lds16(wpg + kt, Bsb + cur * 8192 + tid * 16);
        gload_lds16(wpg + (size_t)64 * K + kt, Bsb + cur * 8192 + 4096 + tid * 16);
      }
      cur ^= 1;
    }
  }

  const int c0o = nt * 128 + wc * 64 + lm;
  float bb[4];
#pragma unroll
  for (int j = 0; j < 4; ++j) bb[j] = bias[c0o + j * 16];
  const int mslot = wr ? cs1 : cs0;  // this wave's 64-row output slot

  if (OUT_MODE < 2) {
#pragma unroll
    for (int i = 0; i < 4; ++i)
#pragma unroll
      for (int j = 0; j < 4; ++j)
#pragma unroll
        for (int p = 0; p < 4; ++p) {
          size_t grow = (size_t)mslot * 64 + (l4 * 4 + i * 16 + p);
          size_t idx = grow * N + (size_t)(c0o + j * 16);
          float v = acc[i][j][p] + bb[j];
          if (SC) v *= 0.125f;  // exact exponent shift; bf16(v/8) == bf16(v)/8
          if (OUT_MODE == 1)
            ((unsigned short*)Cout)[idx] = f2bf(v);
          else
            ((float*)Cout)[idx] = v;
        }
  } else {
    // V^T per-head tiles: vt[(slot*16+h)*4096 + d*64 + t], t = i*16+l4*4+p
    const int hh = (nt * 128 + wc * 64) / 64;
    unsigned short* vt = (unsigned short*)Cout;
    const size_t base = ((size_t)mslot * 16 + hh) * 4096;
#pragma unroll
    for (int j = 0; j < 4; ++j) {
      const int d = lm + j * 16;
#pragma unroll
      for (int i = 0; i < 4; ++i) {
        uint2 wv;
        wv.x = pack2(acc[i][j][0] + bb[j], acc[i][j][1] + bb[j]);
        wv.y = pack2(acc[i][j][2] + bb[j], acc[i][j][3] + bb[j]);
        *(uint2*)(vt + base + (size_t)d * 64 + i * 16 + l4 * 4) = wv;
      }
    }
  }
}

// ----------------------------- fused attention -----------------------------
// One block per (h, b); 8 waves, wave w owns q rows [16w,16w+16).
// Swapped-operand MFMAs so q = lane&15 everywhere; online softmax over r.
// LDS (48KB): kv_s[2][K,V] 32KB; pa_s 16KB; q/sa^T staging overlays.
// Active-review compaction: reviews with mask==1 (when any mask==0 exists in
// row b) have pooled weight exactly 0.0f (expf(-1e30 - max) underflows) ->
// skipped entirely.  Bitmask is uniform per block (depends only on b).
__global__ __launch_bounds__(512, 4) void attn2(
    const unsigned short* __restrict__ qb, const unsigned short* __restrict__ kb,
    const unsigned short* __restrict__ vtg, const int* __restrict__ mask,
    const int* __restrict__ mask2, const float* __restrict__ sa_a,
    const float* __restrict__ sa_b, unsigned short* __restrict__ merged) {
  const int h = (int)blockIdx.x;
  const int b = (int)blockIdx.y;
  const int tid = (int)threadIdx.x;
  const int lane = tid & 63, wave = tid >> 6;
  const int lm = lane & 15, l4 = lane >> 4;
  const int sw = (lm & 7) << 4;

  __shared__ unsigned short kv_s[2][2][64 * 64];  // [buf][0=K [t][d], 1=V^T [d][t]]
  __shared__ unsigned short pa_s[8 * 16 * 64];    // wave-private P/att rows

  char* kvb0 = (char*)kv_s;          // buf stride 16384; V^T at +8192
  char* qreg = (char*)kv_s + 16384;  // q staging region = buf1 (dead after hoist)
  char* satb = (char*)pa_s;          // sa^T staging (dead after hoist)

  // ---- active-review bitmask (uniform across the block) ----
  unsigned am = 0u;
#pragma unroll
  for (int rr = 0; rr < 20; ++rr)
    am |= (mask[b * 20 + rr] == 0) ? (1u << rr) : 0u;
  // az (= some review has mask==0) => only those reviews survive; else all.
  const unsigned act = am ? am : 0xFFFFFu;

  // ---- stage Q into qreg (pre-swizzled source columns) ----
#pragma unroll
  for (int s = 0; s < 2; ++s) {
    int idx = s * 512 + tid, row = idx >> 3, blk = idx & 7;
    int cb = blk ^ (row & 7);
    gload_lds16(qb + (size_t)(b * 128 + row) * 1024 + h * 64 + cb * 8, qreg + idx * 16);
  }
  // ---- stage sa^T into satb: sat[jj][d] = sa_a[d][jj], swizzled ----
#pragma unroll
  for (int s = 0; s < 8; ++s) {
    int idx = s * 512 + tid, jj = idx & 63, d = idx >> 6;
    *(unsigned short*)(satb + jj * 128 + ((d * 2) ^ ((jj & 7) << 4))) =
        f2bf(sa_a[d * 64 + jj]);
  }
  // ---- stage first ACTIVE review K/V into buf0 ----
  const int srow = tid >> 3, sblk = tid & 7;
  const int scb = sblk ^ (srow & 7);
  int r = (int)__builtin_ctz(act);
  unsigned rem = act & (act - 1u);
  gload_lds16(kb + ((size_t)(b * 20 + r) * 64 + srow) * 1024 + h * 64 + scb * 8,
              kvb0 + tid * 16);
  gload_lds16(vtg + ((size_t)(b * 20 + r) * 16 + h) * 4096 + srow * 64 + scb * 8,
              kvb0 + 8192 + tid * 16);

  f32x4 sbv[4];
#pragma unroll
  for (int i = 0; i < 4; ++i) sbv[i] = *(const f32x4*)(sa_b + i * 16 + l4 * 4);

  __syncthreads();  // qreg, satb, buf0 all visible

  // ---- hoist Q B-fragments and sa^T A-fragments to registers ----
  const char* qrp = qreg + (wave * 16 + lm) * 128;
  bf16x8 qf[2];
  qf[0] = *(const bf16x8*)(qrp + ((l4 * 16) ^ sw));
  qf[1] = *(const bf16x8*)(qrp + ((64 + l4 * 16) ^ sw));
  bf16x8 sfr[2][4];
#pragma unroll
  for (int kk = 0; kk < 2; ++kk)
#pragma unroll
    for (int i = 0; i < 4; ++i)
      sfr[kk][i] = *(const bf16x8*)(satb + (i * 16 + lm) * 128 +
                                    ((kk * 64 + l4 * 16) ^ sw));
  asm volatile("s_waitcnt lgkmcnt(0)" ::: "memory");  // hoist reads retired
  __syncthreads();  // all waves done -> qreg/satb reusable as buf1 / P-rows

  char* pw = (char*)pa_s + wave * 2048 + lm * 128;  // wave-private row q=lm

  f32x4 zero4 = {0.f, 0.f, 0.f, 0.f};
  f32x4 Pacc[4];
#pragma unroll
  for (int i = 0; i < 4; ++i) Pacc[i] = zero4;
  float m_run = -3.0e38f, s_run = 0.0f;

  int it = 0;
  for (;;) {
    const int pb = it & 1;
    if (it) __syncthreads();  // buf[pb] staged; all waves done with buf[1-pb]
    const int nr = rem ? (int)__builtin_ctz(rem) : -1;
    if (nr >= 0) {  // stage next active review (flies under this one's compute)
      const int nbuf = pb ^ 1;
      gload_lds16(kb + ((size_t)(b * 20 + nr) * 64 + srow) * 1024 + h * 64 + scb * 8,
                  kvb0 + nbuf * 16384 + tid * 16);
      gload_lds16(vtg + ((size_t)(b * 20 + nr) * 16 + h) * 4096 + srow * 64 + scb * 8,
                  kvb0 + nbuf * 16384 + 8192 + tid * 16);
    }
    const char* kbse = kvb0 + pb * 16384;
    const char* vbse = kvb0 + pb * 16384 + 8192;

    // ---- S^T = mfma(K, Q): rows t, col q (q pre-scaled by 1/8) ----
    f32x4 sc[4];
#pragma unroll
    for (int i = 0; i < 4; ++i) sc[i] = zero4;
    __builtin_amdgcn_s_setprio(1);
#pragma unroll
    for (int kk = 0; kk < 2; ++kk) {
      bf16x8 kf[4];
#pragma unroll
      for (int i = 0; i < 4; ++i)
        kf[i] = *(const bf16x8*)(kbse + (i * 16 + lm) * 128 + ((kk * 64 + l4 * 16) ^ sw));
#pragma unroll
      for (int i = 0; i < 4; ++i)
        sc[i] = __builtin_amdgcn_mfma_f32_16x16x32_bf16(kf[i], qf[kk], sc[i], 0, 0, 0);
    }
    __builtin_amdgcn_s_setprio(0);

    // ---- token mask (scores already scaled) + softmax over t ----
    const int mbase = (b * 20 + r) * 64;
#pragma unroll
    for (int i = 0; i < 4; ++i) {
      int4 m2 = *(const int4*)(mask2 + mbase + i * 16 + l4 * 4);
      sc[i][0] = (m2.x == 0) ? -1e20f : sc[i][0];
      sc[i][1] = (m2.y == 0) ? -1e20f : sc[i][1];
      sc[i][2] = (m2.z == 0) ? -1e20f : sc[i][2];
      sc[i][3] = (m2.w == 0) ? -1e20f : sc[i][3];
    }
    float mx = sc[0][0];
#pragma unroll
    for (int i = 0; i < 4; ++i)
#pragma unroll
      for (int p = 0; p < 4; ++p) mx = fmaxf(mx, sc[i][p]);
    mx = fmaxf(mx, __shfl_xor(mx, 16));
    mx = fmaxf(mx, __shfl_xor(mx, 32));
    float sum = 0.f;
#pragma unroll
    for (int i = 0; i < 4; ++i)
#pragma unroll
      for (int p = 0; p < 4; ++p) {
        float e = __expf(sc[i][p] - mx);
        sc[i][p] = e;
        sum += e;
      }
    sum += __shfl_xor(sum, 16);
    sum += __shfl_xor(sum, 32);
    const float pinv = __builtin_amdgcn_rcpf(sum);

    // ---- P -> wave-private LDS [q][t], packed 8B swizzled writes ----
#pragma unroll
    for (int i = 0; i < 4; ++i) {
      uint2 wv;
      wv.x = pk2_rhu(sc[i][0] * pinv, sc[i][1] * pinv);
      wv.y = pk2_rhu(sc[i][2] * pinv, sc[i][3] * pinv);
      *(uint2*)(pw + ((i * 32 + l4 * 8) ^ sw)) = wv;
    }

    // ---- att^T = mfma(V^T, P): rows d, col q ----
    f32x4 av[4];
#pragma unroll
    for (int i = 0; i < 4; ++i) av[i] = zero4;
    __builtin_amdgcn_s_setprio(1);
#pragma unroll
    for (int kk = 0; kk < 2; ++kk) {
      bf16x8 pf = *(const bf16x8*)(pw + ((kk * 64 + l4 * 16) ^ sw));
      bf16x8 vf[4];
#pragma unroll
      for (int i = 0; i < 4; ++i)
        vf[i] = *(const bf16x8*)(vbse + (i * 16 + lm) * 128 + ((kk * 64 + l4 * 16) ^ sw));
#pragma unroll
      for (int i = 0; i < 4; ++i)
        av[i] = __builtin_amdgcn_mfma_f32_16x16x32_bf16(vf[i], pf, av[i], 0, 0, 0);
    }
    __builtin_amdgcn_s_setprio(0);

    // ---- att -> same wave-private LDS [q][d] (P already consumed) ----
#pragma unroll
    for (int i = 0; i < 4; ++i) {
      uint2 wv;
      wv.x = pk2_rhu(av[i][0], av[i][1]);
      wv.y = pk2_rhu(av[i][2], av[i][3]);
      *(uint2*)(pw + ((i * 32 + l4 * 8) ^ sw)) = wv;
    }

    // ---- e^T = mfma(sa^T, att): rows jj, col q ----
    f32x4 ep[4];
#pragma unroll
    for (int i = 0; i < 4; ++i) ep[i] = zero4;
    __builtin_amdgcn_s_setprio(1);
#pragma unroll
    for (int kk = 0; kk < 2; ++kk) {
      bf16x8 afr = *(const bf16x8*)(pw + ((kk * 64 + l4 * 16) ^ sw));
#pragma unroll
      for (int i = 0; i < 4; ++i)
        ep[i] = __builtin_amdgcn_mfma_f32_16x16x32_bf16(sfr[kk][i], afr, ep[i], 0, 0, 0);
    }
    __builtin_amdgcn_s_setprio(0);
    float a = 0.f;
#pragma unroll
    for (int i = 0; i < 4; ++i)
#pragma unroll
      for (int p = 0; p < 4; ++p) a += fast_tanh(ep[i][p]) * sbv[i][p];
    a += __shfl_xor(a, 16);
    a += __shfl_xor(a, 32);

    // ---- exact online softmax update over active reviews ----
    // All surviving reviews have add_mask == 0, so e_r = a directly.
    const float e_r = a;
    const float mnew = fmaxf(m_run, e_r);
    const float scl = __expf(m_run - mnew);
    const float w = __expf(e_r - mnew);
    s_run = s_run * scl + w;
#pragma unroll
    for (int i = 0; i < 4; ++i)
#pragma unroll
      for (int p = 0; p < 4; ++p) Pacc[i][p] = Pacc[i][p] * scl + w * av[i][p];
    m_run = mnew;

    if (nr < 0) break;
    r = nr;
    rem &= rem - 1u;
    ++it;
  }

  // ---- merged[b*128+q][h*64+d] = bf16(Pacc / s) ----
  const float inv_s = __builtin_amdgcn_rcpf(s_run);
  unsigned short* mrow = merged + (size_t)(b * 128 + wave * 16 + lm) * 1024 + h * 64;
#pragma unroll
  for (int i = 0; i < 4; ++i) {
    uint2 o;
    o.x = pk2_rhu(Pacc[i][0] * inv_s, Pacc[i][1] * inv_s);
    o.y = pk2_rhu(Pacc[i][2] * inv_s, Pacc[i][3] * inv_s);
    *(uint2*)(mrow + i * 16 + l4 * 4) = o;
  }
}

// ---------------------------------------------------------------------------
extern "C" void kernel_launch(void* const* d_in, const int* in_sizes, int n_in,
                              void* d_out, int out_size, void* d_ws, size_t ws_size,
                              hipStream_t stream) {
  (void)in_sizes; (void)n_in; (void)out_size; (void)ws_size;
  const float* query = (const float*)d_in[0];
  const float* key   = (const float*)d_in[1];
  const float* value = (const float*)d_in[2];
  const int*   mask  = (const int*)d_in[3];
  const int*   mask2 = (const int*)d_in[4];
  const float* Wq = (const float*)d_in[5];
  const float* bq = (const float*)d_in[6];
  const float* Wk = (const float*)d_in[7];
  const float* bk = (const float*)d_in[8];
  const float* Wv = (const float*)d_in[9];
  const float* bv = (const float*)d_in[10];
  const float* Wo = (const float*)d_in[11];
  const float* bo = (const float*)d_in[12];
  const float* sa_a = (const float*)d_in[13];
  const float* sa_b = (const float*)d_in[14];

  char* ws = (char*)d_ws;
  size_t off = 0;
  auto carve = [&](size_t bytes) -> char* {
    char* p = ws + off;
    off += (bytes + 255) & ~(size_t)255;
    return p;
  };
  unsigned short* wq_b = (unsigned short*)carve((size_t)1024 * 1024 * 2);
  unsigned short* wk_b = (unsigned short*)carve((size_t)1024 * 1024 * 2);
  unsigned short* wv_b = (unsigned short*)carve((size_t)1024 * 1024 * 2);
  unsigned short* wo_b = (unsigned short*)carve((size_t)1024 * 1024 * 2);
  unsigned short* q_b  = (unsigned short*)carve((size_t)4096 * 1024 * 2);
  unsigned short* k_b  = (unsigned short*)carve((size_t)40960 * 1024 * 2);
  unsigned short* vt_g = (unsigned short*)carve((size_t)40960 * 1024 * 2);
  unsigned short* mrg  = (unsigned short*)carve((size_t)4096 * 1024 * 2);
  int* cmp = (int*)carve(4096);
  // shared compacted-activation buffer (reused K then V); total ws ~264MB =
  // round-1 fat-path footprint (proven available).
  unsigned short* act = (unsigned short*)carve((size_t)40960 * 1024 * 2);

  cvt_w4<<<1024, 256, 0, stream>>>(Wq, Wk, Wv, Wo, wq_b, wk_b, wv_b, wo_b);
  compact_rv<<<1, 64, 0, stream>>>(mask, cmp);

  // Q projection: f32-direct (small)
  gemm_bt<1, 0, 1, 0><<<dim3(32 * 8), 256, 0, stream>>>(query, wq_b, bq, q_b, 1024, 1024, 8, cmp);

  // K projection: compacted cvt -> proven bf16-A GEMM (dense A, slot C-write)
  cvt_act<<<2048, 256, 0, stream>>>(key, act, cmp);
  gemm_bt<1, 1, 0, 1><<<dim3(320 * 8), 256, 0, stream>>>(act, wk_b, bk, k_b, 1024, 1024, 8, cmp);

  // V projection: same act buffer (K-GEMM already consumed it)
  cvt_act<<<2048, 256, 0, stream>>>(value, act, cmp);
  gemm_bt<2, 1, 0, 1><<<dim3(320 * 8), 256, 0, stream>>>(act, wv_b, bv, vt_g, 1024, 1024, 8, cmp);

  attn2<<<dim3(16, 32), 512, 0, stream>>>(q_b, k_b, vt_g, mask, mask2, sa_a, sa_b, mrg);

  // out projection: A (mrg) is bf16 -> proven bf16-A path
  gemm_bt<0, 1, 0, 0><<<dim3(32 * 8), 256, 0, stream>>>(mrg, wo_b, bo, d_out, 1024, 1024, 8, cmp);
}